// Round 6
// baseline (404.023 us; speedup 1.0000x reference)
//
#include <hip/hip_runtime.h>
#include <hip/hip_bf16.h>

#define N_NODES 50000
#define N_EDGES 800000
#define N_GRAPHS 64
#define HID 64
#define SCAN_NB 196  // ceil(50000/256)

static inline size_t align256(size_t x) { return (x + 255) & ~(size_t)255; }

__global__ void zero_i32(int* __restrict__ p, int n) {
    int i = blockIdx.x * blockDim.x + threadIdx.x;
    if (i < n) p[i] = 0;
}

// count incoming edges per destination node
__global__ void deg_kernel(const int* __restrict__ ei, int* __restrict__ cnt) {
    int e = blockIdx.x * blockDim.x + threadIdx.x;
    if (e < N_EDGES) atomicAdd(&cnt[ei[N_EDGES + e]], 1);
}

// phase A: per-block (256-wide) inclusive scan of cnt; block totals to bsum
__global__ __launch_bounds__(256) void scan_a(const int* __restrict__ cnt,
                                              int* __restrict__ incl,
                                              int* __restrict__ bsum) {
    __shared__ int sd[256];
    int t = threadIdx.x;
    int i = blockIdx.x * 256 + t;
    int v = (i < N_NODES) ? cnt[i] : 0;
    sd[t] = v;
    __syncthreads();
    for (int off = 1; off < 256; off <<= 1) {
        int u = (t >= off) ? sd[t - off] : 0;
        __syncthreads();
        sd[t] += u;
        __syncthreads();
    }
    if (i < N_NODES) incl[i] = sd[t];
    if (t == 255) bsum[blockIdx.x] = sd[255];
}

// phase B: single block, exclusive scan of the 196 block sums
__global__ __launch_bounds__(256) void scan_b(const int* __restrict__ bsum,
                                              int* __restrict__ boff) {
    __shared__ int sd[256];
    int t = threadIdx.x;
    int v = (t < SCAN_NB) ? bsum[t] : 0;
    sd[t] = v;
    __syncthreads();
    for (int off = 1; off < 256; off <<= 1) {
        int u = (t >= off) ? sd[t - off] : 0;
        __syncthreads();
        sd[t] += u;
        __syncthreads();
    }
    if (t < SCAN_NB) boff[t] = sd[t] - v;  // exclusive
}

// phase C: writeback row_ptr / fill_ptr / dinv
__global__ void scan_c(const int* __restrict__ cnt, const int* __restrict__ incl,
                       const int* __restrict__ boff, int* __restrict__ row_ptr,
                       int* __restrict__ fill_ptr, float* __restrict__ dinv) {
    int i = blockIdx.x * blockDim.x + threadIdx.x;
    if (i < N_NODES) {
        int c = cnt[i];
        int run = boff[i >> 8] + incl[i];  // inclusive prefix over all nodes
        row_ptr[i + 1] = run;
        fill_ptr[i] = run - c;             // bucket start
        dinv[i] = rsqrtf((float)c + 1.0f);
        if (i == 0) row_ptr[0] = 0;
    }
}

// scatter edge sources into CSR buckets keyed by dst
__global__ void fill_kernel(const int* __restrict__ ei, int* __restrict__ fill_ptr,
                            int* __restrict__ csr_src) {
    int e = blockIdx.x * blockDim.x + threadIdx.x;
    if (e < N_EDGES) {
        int src = ei[e];
        int dst = ei[N_EDGES + e];
        int pos = atomicAdd(&fill_ptr[dst], 1);
        csr_src[pos] = src;
    }
}

// batch is sorted: find first node index with batch >= g, for g = 0..N_GRAPHS
__global__ void gstart_kernel(const int* __restrict__ batch, int* __restrict__ gstart) {
    int g = threadIdx.x;
    if (g <= N_GRAPHS) {
        int lo = 0, hi = N_NODES;
        while (lo < hi) {
            int mid = (lo + hi) >> 1;
            if (batch[mid] < g) lo = mid + 1; else hi = mid;
        }
        gstart[g] = lo;
    }
}

// hw2[row][col] = dinv[row] * sum_k h[row][k] * W[k][col]
// 256 threads = 4 waves; wave computes 8 rows x 64 cols; block = 32 rows.
// Software-pipelined: next k-chunk's 8 independent loads issue before current
// FMAs, hiding L2/L3 latency. Outer loop pinned unroll 1 (round-2 lesson:
// full unroll -> 256 VGPR + spills).
template <int K>
__global__ __launch_bounds__(256) void matmul_kernel(const float* __restrict__ h,
                                                     const float* __restrict__ W,
                                                     const float* __restrict__ dinv,
                                                     float* __restrict__ hw2) {
    __shared__ float sW[K * 64];
    int tid = threadIdx.x;
#pragma unroll 1
    for (int i = tid * 4; i < K * 64; i += 256 * 4)
        *(float4*)&sW[i] = *(const float4*)&W[i];
    __syncthreads();

    int lane = tid & 63;
    int wid = tid >> 6;
    int row0 = blockIdx.x * 32 + wid * 8;

    const float* pr[8];
#pragma unroll
    for (int r = 0; r < 8; ++r)
        pr[r] = h + (size_t)min(row0 + r, N_NODES - 1) * K;

    float4 cur[8];
#pragma unroll
    for (int r = 0; r < 8; ++r) cur[r] = *(const float4*)&pr[r][0];

    float acc[8] = {0.f, 0.f, 0.f, 0.f, 0.f, 0.f, 0.f, 0.f};
#pragma unroll 1
    for (int k = 0; k < K; k += 4) {
        int k4 = (k + 4 < K) ? (k + 4) : k;
        float4 nxt[8];
#pragma unroll
        for (int r = 0; r < 8; ++r) nxt[r] = *(const float4*)&pr[r][k4];
        float w0 = sW[(k + 0) * 64 + lane];
        float w1 = sW[(k + 1) * 64 + lane];
        float w2 = sW[(k + 2) * 64 + lane];
        float w3 = sW[(k + 3) * 64 + lane];
#pragma unroll
        for (int r = 0; r < 8; ++r)
            acc[r] += cur[r].x * w0 + cur[r].y * w1 + cur[r].z * w2 + cur[r].w * w3;
#pragma unroll
        for (int r = 0; r < 8; ++r) cur[r] = nxt[r];
    }
#pragma unroll
    for (int r = 0; r < 8; ++r) {
        int row = row0 + r;
        if (row < N_NODES) hw2[(size_t)row * 64 + lane] = dinv[row] * acc[r];
    }
}

// per node (one wave): edges processed 4 at a time.
// Edge indices pre-loaded coalesced (64 per chunk, one per lane), distributed
// via shfl. ROUND-5 BUG FIX: the shfl loop must have a WAVE-UNIFORM trip count
// (i uniform, bound nE uniform) so ds_bpermute never reads from an
// exec-masked-off lane; only the accumulation is predicated (myi < nE).
__global__ __launch_bounds__(256) void agg_kernel(const float* __restrict__ hw2,
                                                  const int* __restrict__ row_ptr,
                                                  const int* __restrict__ csr_src,
                                                  const float* __restrict__ dinv,
                                                  const float* __restrict__ b,
                                                  float* __restrict__ hout) {
    int node = blockIdx.x * 4 + (threadIdx.x >> 6);
    int lane = threadIdx.x & 63;
    if (node >= N_NODES) return;
    int grp = lane >> 4;   // 0..3 : which edge of the 4-wide batch
    int gl  = lane & 15;   // 0..15: which float4 of the row
    int s = row_ptr[node], e = row_ptr[node + 1];

    float ax = 0.f, ay = 0.f, az = 0.f, aw = 0.f;
    for (int base = s; base < e; base += 64) {
        int nE = min(64, e - base);                          // wave-uniform
        int msrc = (lane < nE) ? csr_src[base + lane] : 0;   // coalesced
#pragma unroll 2
        for (int i = 0; i < nE; i += 4) {                    // uniform trip count
            int myi = i + grp;                               // <= 63 always
            int src = __shfl(msrc, myi, 64);                 // full-exec shfl
            if (myi < nE) {
                float4 v = *(const float4*)&hw2[(size_t)src * 64 + gl * 4];
                ax += v.x; ay += v.y; az += v.z; aw += v.w;
            }
        }
    }
    // sum the 4 groups' partials (dims are aligned across groups)
#pragma unroll
    for (int off = 16; off <= 32; off <<= 1) {
        ax += __shfl_xor(ax, off, 64);
        ay += __shfl_xor(ay, off, 64);
        az += __shfl_xor(az, off, 64);
        aw += __shfl_xor(aw, off, 64);
    }
    // self-loop term (hw2 pre-scaled by dinv[row])
    float4 self = *(const float4*)&hw2[(size_t)node * 64 + gl * 4];
    ax += self.x; ay += self.y; az += self.z; aw += self.w;

    float di = dinv[node];
    float4 bb = *(const float4*)&b[gl * 4];
    float vx = di * ax + bb.x;
    float vy = di * ay + bb.y;
    float vz = di * az + bb.z;
    float vw = di * aw + bb.w;

    float sq = vx * vx + vy * vy + vz * vz + vw * vw;
#pragma unroll
    for (int off = 1; off <= 8; off <<= 1) sq += __shfl_xor(sq, off, 64);
    float inv = 1.0f / fmaxf(sqrtf(sq), 1e-12f);

    if (grp == 0) {
        float4 r;
        r.x = fmaxf(vx * inv, 0.f);
        r.y = fmaxf(vy * inv, 0.f);
        r.z = fmaxf(vz * inv, 0.f);
        r.w = fmaxf(vw * inv, 0.f);
        *(float4*)&hout[(size_t)node * 64 + gl * 4] = r;
    }
}

// one block per graph: mean+max pool over contiguous node range, then 128x32 linear
__global__ __launch_bounds__(256) void pool_linear_kernel(const float* __restrict__ h,
                                                          const int* __restrict__ gstart,
                                                          const float* __restrict__ Wl,
                                                          const float* __restrict__ bl,
                                                          float* __restrict__ out) {
    int g = blockIdx.x;
    int s = gstart[g], e = gstart[g + 1];
    int lane = threadIdx.x & 63;
    int wid = threadIdx.x >> 6;  // 0..3
    float sum = 0.f, mx = -3.4e38f;
    for (int i = s + wid; i < e; i += 4) {
        float v = h[(size_t)i * 64 + lane];
        sum += v;
        mx = fmaxf(mx, v);
    }
    __shared__ float ssum[4][64];
    __shared__ float smx[4][64];
    __shared__ float pooled[128];
    ssum[wid][lane] = sum;
    smx[wid][lane] = mx;
    __syncthreads();
    if (wid == 0) {
        float s4 = ssum[0][lane] + ssum[1][lane] + ssum[2][lane] + ssum[3][lane];
        float m4 = fmaxf(fmaxf(smx[0][lane], smx[1][lane]), fmaxf(smx[2][lane], smx[3][lane]));
        int cntg = e - s;
        float mean = s4 / fmaxf((float)cntg, 1.0f);
        if (cntg == 0) m4 = 0.f;
        pooled[lane] = mean;
        pooled[64 + lane] = m4;
    }
    __syncthreads();
    if (threadIdx.x < 32) {
        int j = threadIdx.x;
        float acc = bl[j];
#pragma unroll 8
        for (int k = 0; k < 128; ++k) acc += pooled[k] * Wl[k * 32 + j];
        out[g * 32 + j] = acc;
    }
}

extern "C" void kernel_launch(void* const* d_in, const int* in_sizes, int n_in,
                              void* d_out, int out_size, void* d_ws, size_t ws_size,
                              hipStream_t stream) {
    const float* x        = (const float*)d_in[0];   // 50000 x 128
    const int*   ei       = (const int*)d_in[1];     // 2 x 800000
    const int*   batch    = (const int*)d_in[2];     // 50000
    const float* W1       = (const float*)d_in[3];   // 128 x 64
    const float* b1       = (const float*)d_in[4];
    const float* W2       = (const float*)d_in[5];   // 64 x 64
    const float* b2       = (const float*)d_in[6];
    const float* W3       = (const float*)d_in[7];   // 64 x 64
    const float* b3       = (const float*)d_in[8];
    const float* Wl       = (const float*)d_in[9];   // 128 x 32
    const float* bl       = (const float*)d_in[10];
    float* out = (float*)d_out;

    char* ws = (char*)d_ws;
    int*   cnt      = (int*)ws;                 ws += align256((size_t)N_NODES * 4);
    int*   incl     = (int*)ws;                 ws += align256((size_t)N_NODES * 4);
    int*   bsum     = (int*)ws;                 ws += align256((size_t)SCAN_NB * 4);
    int*   boff     = (int*)ws;                 ws += align256((size_t)SCAN_NB * 4);
    int*   row_ptr  = (int*)ws;                 ws += align256((size_t)(N_NODES + 1) * 4);
    int*   fill_ptr = (int*)ws;                 ws += align256((size_t)N_NODES * 4);
    float* dinv     = (float*)ws;               ws += align256((size_t)N_NODES * 4);
    int*   gstart   = (int*)ws;                 ws += align256((size_t)(N_GRAPHS + 1) * 4);
    int*   csr_src  = (int*)ws;                 ws += align256((size_t)N_EDGES * 4);
    float* hwb      = (float*)ws;               ws += align256((size_t)N_NODES * 64 * 4);
    float* h1       = (float*)ws;               ws += align256((size_t)N_NODES * 64 * 4);
    float* h2       = (float*)ws;               ws += align256((size_t)N_NODES * 64 * 4);

    hipLaunchKernelGGL(zero_i32, dim3((N_NODES + 255) / 256), dim3(256), 0, stream, cnt, N_NODES);
    hipLaunchKernelGGL(deg_kernel, dim3((N_EDGES + 255) / 256), dim3(256), 0, stream, ei, cnt);
    hipLaunchKernelGGL(scan_a, dim3(SCAN_NB), dim3(256), 0, stream, cnt, incl, bsum);
    hipLaunchKernelGGL(scan_b, dim3(1), dim3(256), 0, stream, bsum, boff);
    hipLaunchKernelGGL(scan_c, dim3(SCAN_NB), dim3(256), 0, stream,
                       cnt, incl, boff, row_ptr, fill_ptr, dinv);
    hipLaunchKernelGGL(fill_kernel, dim3((N_EDGES + 255) / 256), dim3(256), 0, stream,
                       ei, fill_ptr, csr_src);
    hipLaunchKernelGGL(gstart_kernel, dim3(1), dim3(128), 0, stream, batch, gstart);

    const int mm_grid = (N_NODES + 31) / 32;
    const int agg_grid = (N_NODES + 3) / 4;  // 4 waves per block, wave per node

    // layer 1: x(128) @ W1 -> hw2 (dinv-scaled); agg -> h1
    hipLaunchKernelGGL((matmul_kernel<128>), dim3(mm_grid), dim3(256), 0, stream, x, W1, dinv, hwb);
    hipLaunchKernelGGL(agg_kernel, dim3(agg_grid), dim3(256), 0, stream,
                       hwb, row_ptr, csr_src, dinv, b1, h1);
    // layer 2
    hipLaunchKernelGGL((matmul_kernel<64>), dim3(mm_grid), dim3(256), 0, stream, h1, W2, dinv, hwb);
    hipLaunchKernelGGL(agg_kernel, dim3(agg_grid), dim3(256), 0, stream,
                       hwb, row_ptr, csr_src, dinv, b2, h2);
    // layer 3
    hipLaunchKernelGGL((matmul_kernel<64>), dim3(mm_grid), dim3(256), 0, stream, h2, W3, dinv, hwb);
    hipLaunchKernelGGL(agg_kernel, dim3(agg_grid), dim3(256), 0, stream,
                       hwb, row_ptr, csr_src, dinv, b3, h1);

    // pooling + final linear
    hipLaunchKernelGGL(pool_linear_kernel, dim3(N_GRAPHS), dim3(256), 0, stream,
                       h1, gstart, Wl, bl, out);
}

// Round 7
// 348.221 us; speedup vs baseline: 1.1602x; 1.1602x over previous
//
#include <hip/hip_runtime.h>
#include <hip/hip_bf16.h>

#define N_NODES 50000
#define N_EDGES 800000
#define N_GRAPHS 64
#define HID 64
#define SCAN_NB 196  // ceil(50000/256)

static inline size_t align256(size_t x) { return (x + 255) & ~(size_t)255; }

__global__ void zero_i32(int* __restrict__ p, int n) {
    int i = blockIdx.x * blockDim.x + threadIdx.x;
    if (i < n) p[i] = 0;
}

// count incoming edges per destination node
__global__ void deg_kernel(const int* __restrict__ ei, int* __restrict__ cnt) {
    int e = blockIdx.x * blockDim.x + threadIdx.x;
    if (e < N_EDGES) atomicAdd(&cnt[ei[N_EDGES + e]], 1);
}

// phase A: per-block (256-wide) inclusive scan of cnt; block totals to bsum
__global__ __launch_bounds__(256) void scan_a(const int* __restrict__ cnt,
                                              int* __restrict__ incl,
                                              int* __restrict__ bsum) {
    __shared__ int sd[256];
    int t = threadIdx.x;
    int i = blockIdx.x * 256 + t;
    int v = (i < N_NODES) ? cnt[i] : 0;
    sd[t] = v;
    __syncthreads();
    for (int off = 1; off < 256; off <<= 1) {
        int u = (t >= off) ? sd[t - off] : 0;
        __syncthreads();
        sd[t] += u;
        __syncthreads();
    }
    if (i < N_NODES) incl[i] = sd[t];
    if (t == 255) bsum[blockIdx.x] = sd[255];
}

// phase B: single block, exclusive scan of the 196 block sums
__global__ __launch_bounds__(256) void scan_b(const int* __restrict__ bsum,
                                              int* __restrict__ boff) {
    __shared__ int sd[256];
    int t = threadIdx.x;
    int v = (t < SCAN_NB) ? bsum[t] : 0;
    sd[t] = v;
    __syncthreads();
    for (int off = 1; off < 256; off <<= 1) {
        int u = (t >= off) ? sd[t - off] : 0;
        __syncthreads();
        sd[t] += u;
        __syncthreads();
    }
    if (t < SCAN_NB) boff[t] = sd[t] - v;  // exclusive
}

// phase C: writeback row_ptr / fill_ptr / dinv
__global__ void scan_c(const int* __restrict__ cnt, const int* __restrict__ incl,
                       const int* __restrict__ boff, int* __restrict__ row_ptr,
                       int* __restrict__ fill_ptr, float* __restrict__ dinv) {
    int i = blockIdx.x * blockDim.x + threadIdx.x;
    if (i < N_NODES) {
        int c = cnt[i];
        int run = boff[i >> 8] + incl[i];  // inclusive prefix over all nodes
        row_ptr[i + 1] = run;
        fill_ptr[i] = run - c;             // bucket start
        dinv[i] = rsqrtf((float)c + 1.0f);
        if (i == 0) row_ptr[0] = 0;
    }
}

// scatter edge sources into CSR buckets keyed by dst
__global__ void fill_kernel(const int* __restrict__ ei, int* __restrict__ fill_ptr,
                            int* __restrict__ csr_src) {
    int e = blockIdx.x * blockDim.x + threadIdx.x;
    if (e < N_EDGES) {
        int src = ei[e];
        int dst = ei[N_EDGES + e];
        int pos = atomicAdd(&fill_ptr[dst], 1);
        csr_src[pos] = src;
    }
}

// batch is sorted: find first node index with batch >= g, for g = 0..N_GRAPHS
__global__ void gstart_kernel(const int* __restrict__ batch, int* __restrict__ gstart) {
    int g = threadIdx.x;
    if (g <= N_GRAPHS) {
        int lo = 0, hi = N_NODES;
        while (lo < hi) {
            int mid = (lo + hi) >> 1;
            if (batch[mid] < g) lo = mid + 1; else hi = mid;
        }
        gstart[g] = lo;
    }
}

// hw2[row][col] = dinv[row] * sum_k h[row][k] * W[k][col]
// Tile kernel: block = 256 threads (4 waves), 64 rows per block.
// BOTH W and the 64-row h-tile staged in LDS via coalesced per-lane float4
// loads (round-6 lesson: wave-uniform global loads get scalarized ->
// lgkmcnt serialization with LDS reads; never load broadcast data from
// global in the inner loop). Compute reads: sW lane-indexed (conflict-free),
// sH uniform (broadcast, free). Wave computes 16 rows x 64 cols.
template <int K>
__global__ __launch_bounds__(256) void matmul_kernel(const float* __restrict__ h,
                                                     const float* __restrict__ W,
                                                     const float* __restrict__ dinv,
                                                     float* __restrict__ hw2) {
    constexpr int KC = K / 4;  // float4s per row
    __shared__ float sW[K * 64];
    __shared__ float sH[64 * K];
    int tid = threadIdx.x;
    int r0 = blockIdx.x * 64;

#pragma unroll 1
    for (int i = tid * 4; i < K * 64; i += 256 * 4)
        *(float4*)&sW[i] = *(const float4*)&W[i];
#pragma unroll 1
    for (int i = tid; i < 64 * KC; i += 256) {
        int rl = i / KC;          // local row (KC is power of 2 -> shift)
        int kc = i - rl * KC;
        int grow = min(r0 + rl, N_NODES - 1);  // clamp: safe read, write guarded
        *(float4*)&sH[rl * K + kc * 4] = *(const float4*)&h[(size_t)grow * K + kc * 4];
    }
    __syncthreads();

    int lane = tid & 63;
    int wid = tid >> 6;
    int rbase = wid * 16;

    float acc[16];
#pragma unroll
    for (int r = 0; r < 16; ++r) acc[r] = 0.f;

#pragma unroll 1
    for (int k = 0; k < K; k += 4) {
        float w0 = sW[(k + 0) * 64 + lane];
        float w1 = sW[(k + 1) * 64 + lane];
        float w2 = sW[(k + 2) * 64 + lane];
        float w3 = sW[(k + 3) * 64 + lane];
#pragma unroll
        for (int r = 0; r < 16; ++r) {
            float4 hh = *(const float4*)&sH[(rbase + r) * K + k];
            acc[r] += hh.x * w0 + hh.y * w1 + hh.z * w2 + hh.w * w3;
        }
    }
#pragma unroll
    for (int r = 0; r < 16; ++r) {
        int grow = r0 + rbase + r;
        if (grow < N_NODES) hw2[(size_t)grow * 64 + lane] = dinv[grow] * acc[r];
    }
}

// per node (one wave): edges processed 4 at a time.
// Edge indices pre-loaded coalesced (64 per chunk, one per lane), distributed
// via shfl with a WAVE-UNIFORM trip count (round-5 lesson: shfl from an
// exec-masked-off lane is undefined); only the accumulation is predicated.
__global__ __launch_bounds__(256) void agg_kernel(const float* __restrict__ hw2,
                                                  const int* __restrict__ row_ptr,
                                                  const int* __restrict__ csr_src,
                                                  const float* __restrict__ dinv,
                                                  const float* __restrict__ b,
                                                  float* __restrict__ hout) {
    int node = blockIdx.x * 4 + (threadIdx.x >> 6);
    int lane = threadIdx.x & 63;
    if (node >= N_NODES) return;
    int grp = lane >> 4;   // 0..3 : which edge of the 4-wide batch
    int gl  = lane & 15;   // 0..15: which float4 of the row
    int s = row_ptr[node], e = row_ptr[node + 1];

    float ax = 0.f, ay = 0.f, az = 0.f, aw = 0.f;
    for (int base = s; base < e; base += 64) {
        int nE = min(64, e - base);                          // wave-uniform
        int msrc = (lane < nE) ? csr_src[base + lane] : 0;   // coalesced
#pragma unroll 2
        for (int i = 0; i < nE; i += 4) {                    // uniform trip count
            int myi = i + grp;                               // <= 63 always
            int src = __shfl(msrc, myi, 64);                 // full-exec shfl
            if (myi < nE) {
                float4 v = *(const float4*)&hw2[(size_t)src * 64 + gl * 4];
                ax += v.x; ay += v.y; az += v.z; aw += v.w;
            }
        }
    }
    // sum the 4 groups' partials (dims are aligned across groups)
#pragma unroll
    for (int off = 16; off <= 32; off <<= 1) {
        ax += __shfl_xor(ax, off, 64);
        ay += __shfl_xor(ay, off, 64);
        az += __shfl_xor(az, off, 64);
        aw += __shfl_xor(aw, off, 64);
    }
    // self-loop term (hw2 pre-scaled by dinv[row])
    float4 self = *(const float4*)&hw2[(size_t)node * 64 + gl * 4];
    ax += self.x; ay += self.y; az += self.z; aw += self.w;

    float di = dinv[node];
    float4 bb = *(const float4*)&b[gl * 4];
    float vx = di * ax + bb.x;
    float vy = di * ay + bb.y;
    float vz = di * az + bb.z;
    float vw = di * aw + bb.w;

    float sq = vx * vx + vy * vy + vz * vz + vw * vw;
#pragma unroll
    for (int off = 1; off <= 8; off <<= 1) sq += __shfl_xor(sq, off, 64);
    float inv = 1.0f / fmaxf(sqrtf(sq), 1e-12f);

    if (grp == 0) {
        float4 r;
        r.x = fmaxf(vx * inv, 0.f);
        r.y = fmaxf(vy * inv, 0.f);
        r.z = fmaxf(vz * inv, 0.f);
        r.w = fmaxf(vw * inv, 0.f);
        *(float4*)&hout[(size_t)node * 64 + gl * 4] = r;
    }
}

// one block per graph: mean+max pool over contiguous node range, then 128x32 linear
__global__ __launch_bounds__(256) void pool_linear_kernel(const float* __restrict__ h,
                                                          const int* __restrict__ gstart,
                                                          const float* __restrict__ Wl,
                                                          const float* __restrict__ bl,
                                                          float* __restrict__ out) {
    int g = blockIdx.x;
    int s = gstart[g], e = gstart[g + 1];
    int lane = threadIdx.x & 63;
    int wid = threadIdx.x >> 6;  // 0..3
    float sum = 0.f, mx = -3.4e38f;
    for (int i = s + wid; i < e; i += 4) {
        float v = h[(size_t)i * 64 + lane];
        sum += v;
        mx = fmaxf(mx, v);
    }
    __shared__ float ssum[4][64];
    __shared__ float smx[4][64];
    __shared__ float pooled[128];
    ssum[wid][lane] = sum;
    smx[wid][lane] = mx;
    __syncthreads();
    if (wid == 0) {
        float s4 = ssum[0][lane] + ssum[1][lane] + ssum[2][lane] + ssum[3][lane];
        float m4 = fmaxf(fmaxf(smx[0][lane], smx[1][lane]), fmaxf(smx[2][lane], smx[3][lane]));
        int cntg = e - s;
        float mean = s4 / fmaxf((float)cntg, 1.0f);
        if (cntg == 0) m4 = 0.f;
        pooled[lane] = mean;
        pooled[64 + lane] = m4;
    }
    __syncthreads();
    if (threadIdx.x < 32) {
        int j = threadIdx.x;
        float acc = bl[j];
#pragma unroll 8
        for (int k = 0; k < 128; ++k) acc += pooled[k] * Wl[k * 32 + j];
        out[g * 32 + j] = acc;
    }
}

extern "C" void kernel_launch(void* const* d_in, const int* in_sizes, int n_in,
                              void* d_out, int out_size, void* d_ws, size_t ws_size,
                              hipStream_t stream) {
    const float* x        = (const float*)d_in[0];   // 50000 x 128
    const int*   ei       = (const int*)d_in[1];     // 2 x 800000
    const int*   batch    = (const int*)d_in[2];     // 50000
    const float* W1       = (const float*)d_in[3];   // 128 x 64
    const float* b1       = (const float*)d_in[4];
    const float* W2       = (const float*)d_in[5];   // 64 x 64
    const float* b2       = (const float*)d_in[6];
    const float* W3       = (const float*)d_in[7];   // 64 x 64
    const float* b3       = (const float*)d_in[8];
    const float* Wl       = (const float*)d_in[9];   // 128 x 32
    const float* bl       = (const float*)d_in[10];
    float* out = (float*)d_out;

    char* ws = (char*)d_ws;
    int*   cnt      = (int*)ws;                 ws += align256((size_t)N_NODES * 4);
    int*   incl     = (int*)ws;                 ws += align256((size_t)N_NODES * 4);
    int*   bsum     = (int*)ws;                 ws += align256((size_t)SCAN_NB * 4);
    int*   boff     = (int*)ws;                 ws += align256((size_t)SCAN_NB * 4);
    int*   row_ptr  = (int*)ws;                 ws += align256((size_t)(N_NODES + 1) * 4);
    int*   fill_ptr = (int*)ws;                 ws += align256((size_t)N_NODES * 4);
    float* dinv     = (float*)ws;               ws += align256((size_t)N_NODES * 4);
    int*   gstart   = (int*)ws;                 ws += align256((size_t)(N_GRAPHS + 1) * 4);
    int*   csr_src  = (int*)ws;                 ws += align256((size_t)N_EDGES * 4);
    float* hwb      = (float*)ws;               ws += align256((size_t)N_NODES * 64 * 4);
    float* h1       = (float*)ws;               ws += align256((size_t)N_NODES * 64 * 4);
    float* h2       = (float*)ws;               ws += align256((size_t)N_NODES * 64 * 4);

    hipLaunchKernelGGL(zero_i32, dim3((N_NODES + 255) / 256), dim3(256), 0, stream, cnt, N_NODES);
    hipLaunchKernelGGL(deg_kernel, dim3((N_EDGES + 255) / 256), dim3(256), 0, stream, ei, cnt);
    hipLaunchKernelGGL(scan_a, dim3(SCAN_NB), dim3(256), 0, stream, cnt, incl, bsum);
    hipLaunchKernelGGL(scan_b, dim3(1), dim3(256), 0, stream, bsum, boff);
    hipLaunchKernelGGL(scan_c, dim3(SCAN_NB), dim3(256), 0, stream,
                       cnt, incl, boff, row_ptr, fill_ptr, dinv);
    hipLaunchKernelGGL(fill_kernel, dim3((N_EDGES + 255) / 256), dim3(256), 0, stream,
                       ei, fill_ptr, csr_src);
    hipLaunchKernelGGL(gstart_kernel, dim3(1), dim3(128), 0, stream, batch, gstart);

    const int mm_grid = (N_NODES + 63) / 64;
    const int agg_grid = (N_NODES + 3) / 4;  // 4 waves per block, wave per node

    // layer 1: x(128) @ W1 -> hw2 (dinv-scaled); agg -> h1
    hipLaunchKernelGGL((matmul_kernel<128>), dim3(mm_grid), dim3(256), 0, stream, x, W1, dinv, hwb);
    hipLaunchKernelGGL(agg_kernel, dim3(agg_grid), dim3(256), 0, stream,
                       hwb, row_ptr, csr_src, dinv, b1, h1);
    // layer 2
    hipLaunchKernelGGL((matmul_kernel<64>), dim3(mm_grid), dim3(256), 0, stream, h1, W2, dinv, hwb);
    hipLaunchKernelGGL(agg_kernel, dim3(agg_grid), dim3(256), 0, stream,
                       hwb, row_ptr, csr_src, dinv, b2, h2);
    // layer 3
    hipLaunchKernelGGL((matmul_kernel<64>), dim3(mm_grid), dim3(256), 0, stream, h2, W3, dinv, hwb);
    hipLaunchKernelGGL(agg_kernel, dim3(agg_grid), dim3(256), 0, stream,
                       hwb, row_ptr, csr_src, dinv, b3, h1);

    // pooling + final linear
    hipLaunchKernelGGL(pool_linear_kernel, dim3(N_GRAPHS), dim3(256), 0, stream,
                       h1, gstart, Wl, bl, out);
}

// Round 8
// 307.503 us; speedup vs baseline: 1.3139x; 1.1324x over previous
//
#include <hip/hip_runtime.h>
#include <hip/hip_bf16.h>

#define N_NODES 50000
#define N_EDGES 800000
#define N_GRAPHS 64
#define HID 64
#define SCAN_NB 196  // ceil(50000/256)

static inline size_t align256(size_t x) { return (x + 255) & ~(size_t)255; }

__global__ void zero_i32(int* __restrict__ p, int n) {
    int i = blockIdx.x * blockDim.x + threadIdx.x;
    if (i < n) p[i] = 0;
}

// count incoming edges per destination node
__global__ void deg_kernel(const int* __restrict__ ei, int* __restrict__ cnt) {
    int e = blockIdx.x * blockDim.x + threadIdx.x;
    if (e < N_EDGES) atomicAdd(&cnt[ei[N_EDGES + e]], 1);
}

// phase A: per-block (256-wide) inclusive scan of cnt; block totals to bsum
__global__ __launch_bounds__(256) void scan_a(const int* __restrict__ cnt,
                                              int* __restrict__ incl,
                                              int* __restrict__ bsum) {
    __shared__ int sd[256];
    int t = threadIdx.x;
    int i = blockIdx.x * 256 + t;
    int v = (i < N_NODES) ? cnt[i] : 0;
    sd[t] = v;
    __syncthreads();
    for (int off = 1; off < 256; off <<= 1) {
        int u = (t >= off) ? sd[t - off] : 0;
        __syncthreads();
        sd[t] += u;
        __syncthreads();
    }
    if (i < N_NODES) incl[i] = sd[t];
    if (t == 255) bsum[blockIdx.x] = sd[255];
}

// phase B: single block, exclusive scan of the 196 block sums
__global__ __launch_bounds__(256) void scan_b(const int* __restrict__ bsum,
                                              int* __restrict__ boff) {
    __shared__ int sd[256];
    int t = threadIdx.x;
    int v = (t < SCAN_NB) ? bsum[t] : 0;
    sd[t] = v;
    __syncthreads();
    for (int off = 1; off < 256; off <<= 1) {
        int u = (t >= off) ? sd[t - off] : 0;
        __syncthreads();
        sd[t] += u;
        __syncthreads();
    }
    if (t < SCAN_NB) boff[t] = sd[t] - v;  // exclusive
}

// phase C: writeback row_ptr / fill_ptr / dinv
__global__ void scan_c(const int* __restrict__ cnt, const int* __restrict__ incl,
                       const int* __restrict__ boff, int* __restrict__ row_ptr,
                       int* __restrict__ fill_ptr, float* __restrict__ dinv) {
    int i = blockIdx.x * blockDim.x + threadIdx.x;
    if (i < N_NODES) {
        int c = cnt[i];
        int run = boff[i >> 8] + incl[i];  // inclusive prefix over all nodes
        row_ptr[i + 1] = run;
        fill_ptr[i] = run - c;             // bucket start
        dinv[i] = rsqrtf((float)c + 1.0f);
        if (i == 0) row_ptr[0] = 0;
    }
}

// scatter edge sources into CSR buckets keyed by dst
__global__ void fill_kernel(const int* __restrict__ ei, int* __restrict__ fill_ptr,
                            int* __restrict__ csr_src) {
    int e = blockIdx.x * blockDim.x + threadIdx.x;
    if (e < N_EDGES) {
        int src = ei[e];
        int dst = ei[N_EDGES + e];
        int pos = atomicAdd(&fill_ptr[dst], 1);
        csr_src[pos] = src;
    }
}

// batch is sorted: find first node index with batch >= g, for g = 0..N_GRAPHS
__global__ void gstart_kernel(const int* __restrict__ batch, int* __restrict__ gstart) {
    int g = threadIdx.x;
    if (g <= N_GRAPHS) {
        int lo = 0, hi = N_NODES;
        while (lo < hi) {
            int mid = (lo + hi) >> 1;
            if (batch[mid] < g) lo = mid + 1; else hi = mid;
        }
        gstart[g] = lo;
    }
}

// hw2[row][col] = dinv[row] * sum_k h[row][k] * W[k][col]
// Tile kernel: block = 256 threads (4 waves), 64 rows per block.
// BOTH W and the 64-row h-tile staged in LDS via coalesced per-lane float4
// loads (round-6 lesson: wave-uniform global loads get scalarized ->
// lgkmcnt serialization with LDS reads). Wave computes 16 rows x 64 cols.
template <int K>
__global__ __launch_bounds__(256) void matmul_kernel(const float* __restrict__ h,
                                                     const float* __restrict__ W,
                                                     const float* __restrict__ dinv,
                                                     float* __restrict__ hw2) {
    constexpr int KC = K / 4;  // float4s per row
    __shared__ float sW[K * 64];
    __shared__ float sH[64 * K];
    int tid = threadIdx.x;
    int r0 = blockIdx.x * 64;

#pragma unroll 1
    for (int i = tid * 4; i < K * 64; i += 256 * 4)
        *(float4*)&sW[i] = *(const float4*)&W[i];
#pragma unroll 1
    for (int i = tid; i < 64 * KC; i += 256) {
        int rl = i / KC;
        int kc = i - rl * KC;
        int grow = min(r0 + rl, N_NODES - 1);  // clamp: safe read, write guarded
        *(float4*)&sH[rl * K + kc * 4] = *(const float4*)&h[(size_t)grow * K + kc * 4];
    }
    __syncthreads();

    int lane = tid & 63;
    int wid = tid >> 6;
    int rbase = wid * 16;

    float acc[16];
#pragma unroll
    for (int r = 0; r < 16; ++r) acc[r] = 0.f;

#pragma unroll 1
    for (int k = 0; k < K; k += 4) {
        float w0 = sW[(k + 0) * 64 + lane];
        float w1 = sW[(k + 1) * 64 + lane];
        float w2 = sW[(k + 2) * 64 + lane];
        float w3 = sW[(k + 3) * 64 + lane];
#pragma unroll
        for (int r = 0; r < 16; ++r) {
            float4 hh = *(const float4*)&sH[(rbase + r) * K + k];
            acc[r] += hh.x * w0 + hh.y * w1 + hh.z * w2 + hh.w * w3;
        }
    }
#pragma unroll
    for (int r = 0; r < 16; ++r) {
        int grow = r0 + rbase + r;
        if (grow < N_NODES) hw2[(size_t)grow * 64 + lane] = dinv[grow] * acc[r];
    }
}

// per node (one wave): edges processed 4 at a time.
// Edge indices pre-loaded coalesced (64 per chunk, one per lane), distributed
// via shfl with a WAVE-UNIFORM trip count (round-5 lesson: shfl from an
// exec-masked-off lane is undefined); only the accumulation is predicated.
__global__ __launch_bounds__(256) void agg_kernel(const float* __restrict__ hw2,
                                                  const int* __restrict__ row_ptr,
                                                  const int* __restrict__ csr_src,
                                                  const float* __restrict__ dinv,
                                                  const float* __restrict__ b,
                                                  float* __restrict__ hout) {
    int node = blockIdx.x * 4 + (threadIdx.x >> 6);
    int lane = threadIdx.x & 63;
    if (node >= N_NODES) return;
    int grp = lane >> 4;   // 0..3 : which edge of the 4-wide batch
    int gl  = lane & 15;   // 0..15: which float4 of the row
    int s = row_ptr[node], e = row_ptr[node + 1];

    float ax = 0.f, ay = 0.f, az = 0.f, aw = 0.f;
    for (int base = s; base < e; base += 64) {
        int nE = min(64, e - base);                          // wave-uniform
        int msrc = (lane < nE) ? csr_src[base + lane] : 0;   // coalesced
#pragma unroll 2
        for (int i = 0; i < nE; i += 4) {                    // uniform trip count
            int myi = i + grp;                               // <= 63 always
            int src = __shfl(msrc, myi, 64);                 // full-exec shfl
            if (myi < nE) {
                float4 v = *(const float4*)&hw2[(size_t)src * 64 + gl * 4];
                ax += v.x; ay += v.y; az += v.z; aw += v.w;
            }
        }
    }
    // sum the 4 groups' partials (dims are aligned across groups)
#pragma unroll
    for (int off = 16; off <= 32; off <<= 1) {
        ax += __shfl_xor(ax, off, 64);
        ay += __shfl_xor(ay, off, 64);
        az += __shfl_xor(az, off, 64);
        aw += __shfl_xor(aw, off, 64);
    }
    // self-loop term (hw2 pre-scaled by dinv[row])
    float4 self = *(const float4*)&hw2[(size_t)node * 64 + gl * 4];
    ax += self.x; ay += self.y; az += self.z; aw += self.w;

    float di = dinv[node];
    float4 bb = *(const float4*)&b[gl * 4];
    float vx = di * ax + bb.x;
    float vy = di * ay + bb.y;
    float vz = di * az + bb.z;
    float vw = di * aw + bb.w;

    float sq = vx * vx + vy * vy + vz * vz + vw * vw;
#pragma unroll
    for (int off = 1; off <= 8; off <<= 1) sq += __shfl_xor(sq, off, 64);
    float inv = 1.0f / fmaxf(sqrtf(sq), 1e-12f);

    if (grp == 0) {
        float4 r;
        r.x = fmaxf(vx * inv, 0.f);
        r.y = fmaxf(vy * inv, 0.f);
        r.z = fmaxf(vz * inv, 0.f);
        r.w = fmaxf(vw * inv, 0.f);
        *(float4*)&hout[(size_t)node * 64 + gl * 4] = r;
    }
}

// Phase-1 pooling: 782 blocks x 4 waves; wave owns 16 consecutive nodes,
// lane = dim. batch is sorted -> running (graph,sum,max) with atomic flush
// on graph transition. Values are post-ReLU >= 0, so atomicMax on the int
// bit pattern is order-preserving and init-0 matches the empty-graph guard.
__global__ __launch_bounds__(256) void pool_partial_kernel(const float* __restrict__ h,
                                                           const int* __restrict__ batch,
                                                           float* __restrict__ gsum,
                                                           float* __restrict__ gmax) {
    int wid = threadIdx.x >> 6, lane = threadIdx.x & 63;
    int i0 = blockIdx.x * 64 + wid * 16;
    if (i0 >= N_NODES) return;
    int i1 = min(i0 + 16, N_NODES);
    int gcur = batch[i0];
    float sum = 0.f, mx = 0.f;
    for (int i = i0; i < i1; ++i) {
        int g = batch[i];
        if (g != gcur) {
            atomicAdd(&gsum[gcur * 64 + lane], sum);
            atomicMax((int*)&gmax[gcur * 64 + lane], __float_as_int(mx));
            sum = 0.f; mx = 0.f; gcur = g;
        }
        float v = h[(size_t)i * 64 + lane];
        sum += v;
        mx = fmaxf(mx, v);
    }
    atomicAdd(&gsum[gcur * 64 + lane], sum);
    atomicMax((int*)&gmax[gcur * 64 + lane], __float_as_int(mx));
}

// Phase-2: one block per graph; mean + concat + 128x32 linear.
__global__ __launch_bounds__(128) void linear_kernel(const float* __restrict__ gsum,
                                                     const float* __restrict__ gmax,
                                                     const int* __restrict__ gstart,
                                                     const float* __restrict__ Wl,
                                                     const float* __restrict__ bl,
                                                     float* __restrict__ out) {
    int g = blockIdx.x;
    __shared__ float pooled[128];
    int t = threadIdx.x;
    if (t < 64) {
        int cnt = gstart[g + 1] - gstart[g];
        pooled[t] = gsum[g * 64 + t] / fmaxf((float)cnt, 1.0f);
    } else {
        pooled[t] = gmax[g * 64 + (t - 64)];
    }
    __syncthreads();
    if (t < 32) {
        float acc = bl[t];
#pragma unroll 8
        for (int k = 0; k < 128; ++k) acc += pooled[k] * Wl[k * 32 + t];
        out[g * 32 + t] = acc;
    }
}

extern "C" void kernel_launch(void* const* d_in, const int* in_sizes, int n_in,
                              void* d_out, int out_size, void* d_ws, size_t ws_size,
                              hipStream_t stream) {
    const float* x        = (const float*)d_in[0];   // 50000 x 128
    const int*   ei       = (const int*)d_in[1];     // 2 x 800000
    const int*   batch    = (const int*)d_in[2];     // 50000
    const float* W1       = (const float*)d_in[3];   // 128 x 64
    const float* b1       = (const float*)d_in[4];
    const float* W2       = (const float*)d_in[5];   // 64 x 64
    const float* b2       = (const float*)d_in[6];
    const float* W3       = (const float*)d_in[7];   // 64 x 64
    const float* b3       = (const float*)d_in[8];
    const float* Wl       = (const float*)d_in[9];   // 128 x 32
    const float* bl       = (const float*)d_in[10];
    float* out = (float*)d_out;

    char* ws = (char*)d_ws;
    int*   cnt      = (int*)ws;                 ws += align256((size_t)N_NODES * 4);
    int*   incl     = (int*)ws;                 ws += align256((size_t)N_NODES * 4);
    int*   bsum     = (int*)ws;                 ws += align256((size_t)SCAN_NB * 4);
    int*   boff     = (int*)ws;                 ws += align256((size_t)SCAN_NB * 4);
    int*   row_ptr  = (int*)ws;                 ws += align256((size_t)(N_NODES + 1) * 4);
    int*   fill_ptr = (int*)ws;                 ws += align256((size_t)N_NODES * 4);
    float* dinv     = (float*)ws;               ws += align256((size_t)N_NODES * 4);
    int*   gstart   = (int*)ws;                 ws += align256((size_t)(N_GRAPHS + 1) * 4);
    float* gsum     = (float*)ws;               ws += align256((size_t)N_GRAPHS * 64 * 4);
    float* gmax     = (float*)ws;               ws += align256((size_t)N_GRAPHS * 64 * 4);
    int*   csr_src  = (int*)ws;                 ws += align256((size_t)N_EDGES * 4);
    float* hwb      = (float*)ws;               ws += align256((size_t)N_NODES * 64 * 4);
    float* h1       = (float*)ws;               ws += align256((size_t)N_NODES * 64 * 4);
    float* h2       = (float*)ws;               ws += align256((size_t)N_NODES * 64 * 4);

    hipLaunchKernelGGL(zero_i32, dim3((N_NODES + 255) / 256), dim3(256), 0, stream, cnt, N_NODES);
    // zero gsum+gmax (contiguous, 2*4096 floats)
    hipLaunchKernelGGL(zero_i32, dim3((2 * N_GRAPHS * 64 + 255) / 256), dim3(256), 0, stream,
                       (int*)gsum, 2 * N_GRAPHS * 64);
    hipLaunchKernelGGL(deg_kernel, dim3((N_EDGES + 255) / 256), dim3(256), 0, stream, ei, cnt);
    hipLaunchKernelGGL(scan_a, dim3(SCAN_NB), dim3(256), 0, stream, cnt, incl, bsum);
    hipLaunchKernelGGL(scan_b, dim3(1), dim3(256), 0, stream, bsum, boff);
    hipLaunchKernelGGL(scan_c, dim3(SCAN_NB), dim3(256), 0, stream,
                       cnt, incl, boff, row_ptr, fill_ptr, dinv);
    hipLaunchKernelGGL(fill_kernel, dim3((N_EDGES + 255) / 256), dim3(256), 0, stream,
                       ei, fill_ptr, csr_src);
    hipLaunchKernelGGL(gstart_kernel, dim3(1), dim3(128), 0, stream, batch, gstart);

    const int mm_grid = (N_NODES + 63) / 64;
    const int agg_grid = (N_NODES + 3) / 4;  // 4 waves per block, wave per node

    // layer 1: x(128) @ W1 -> hw2 (dinv-scaled); agg -> h1
    hipLaunchKernelGGL((matmul_kernel<128>), dim3(mm_grid), dim3(256), 0, stream, x, W1, dinv, hwb);
    hipLaunchKernelGGL(agg_kernel, dim3(agg_grid), dim3(256), 0, stream,
                       hwb, row_ptr, csr_src, dinv, b1, h1);
    // layer 2
    hipLaunchKernelGGL((matmul_kernel<64>), dim3(mm_grid), dim3(256), 0, stream, h1, W2, dinv, hwb);
    hipLaunchKernelGGL(agg_kernel, dim3(agg_grid), dim3(256), 0, stream,
                       hwb, row_ptr, csr_src, dinv, b2, h2);
    // layer 3
    hipLaunchKernelGGL((matmul_kernel<64>), dim3(mm_grid), dim3(256), 0, stream, h2, W3, dinv, hwb);
    hipLaunchKernelGGL(agg_kernel, dim3(agg_grid), dim3(256), 0, stream,
                       hwb, row_ptr, csr_src, dinv, b3, h1);

    // two-phase pooling + final linear
    hipLaunchKernelGGL(pool_partial_kernel, dim3((N_NODES + 63) / 64), dim3(256), 0, stream,
                       h1, batch, gsum, gmax);
    hipLaunchKernelGGL(linear_kernel, dim3(N_GRAPHS), dim3(128), 0, stream,
                       gsum, gmax, gstart, Wl, bl, out);
}

// Round 9
// 293.840 us; speedup vs baseline: 1.3750x; 1.0465x over previous
//
#include <hip/hip_runtime.h>
#include <hip/hip_bf16.h>

#define N_NODES 50000
#define N_EDGES 800000
#define N_GRAPHS 64
#define HID 64
#define SCAN_NB 196  // ceil(50000/256)
#define FILL_RANGES 8
#define RANGE_SIZE ((N_NODES + FILL_RANGES - 1) / FILL_RANGES)  // 6250

static inline size_t align256(size_t x) { return (x + 255) & ~(size_t)255; }

__global__ void zero_i32(int* __restrict__ p, int n) {
    int i = blockIdx.x * blockDim.x + threadIdx.x;
    if (i < n) p[i] = 0;
}

// count incoming edges per destination node
__global__ void deg_kernel(const int* __restrict__ ei, int* __restrict__ cnt) {
    int e = blockIdx.x * blockDim.x + threadIdx.x;
    if (e < N_EDGES) atomicAdd(&cnt[ei[N_EDGES + e]], 1);
}

// phase A: per-block (256-wide) inclusive scan of cnt; block totals to bsum
__global__ __launch_bounds__(256) void scan_a(const int* __restrict__ cnt,
                                              int* __restrict__ incl,
                                              int* __restrict__ bsum) {
    __shared__ int sd[256];
    int t = threadIdx.x;
    int i = blockIdx.x * 256 + t;
    int v = (i < N_NODES) ? cnt[i] : 0;
    sd[t] = v;
    __syncthreads();
    for (int off = 1; off < 256; off <<= 1) {
        int u = (t >= off) ? sd[t - off] : 0;
        __syncthreads();
        sd[t] += u;
        __syncthreads();
    }
    if (i < N_NODES) incl[i] = sd[t];
    if (t == 255) bsum[blockIdx.x] = sd[255];
}

// phase B: single block, exclusive scan of the 196 block sums
__global__ __launch_bounds__(256) void scan_b(const int* __restrict__ bsum,
                                              int* __restrict__ boff) {
    __shared__ int sd[256];
    int t = threadIdx.x;
    int v = (t < SCAN_NB) ? bsum[t] : 0;
    sd[t] = v;
    __syncthreads();
    for (int off = 1; off < 256; off <<= 1) {
        int u = (t >= off) ? sd[t - off] : 0;
        __syncthreads();
        sd[t] += u;
        __syncthreads();
    }
    if (t < SCAN_NB) boff[t] = sd[t] - v;  // exclusive
}

// phase C: writeback row_ptr / fill_ptr / dinv
__global__ void scan_c(const int* __restrict__ cnt, const int* __restrict__ incl,
                       const int* __restrict__ boff, int* __restrict__ row_ptr,
                       int* __restrict__ fill_ptr, float* __restrict__ dinv) {
    int i = blockIdx.x * blockDim.x + threadIdx.x;
    if (i < N_NODES) {
        int c = cnt[i];
        int run = boff[i >> 8] + incl[i];  // inclusive prefix over all nodes
        row_ptr[i + 1] = run;
        fill_ptr[i] = run - c;             // bucket start
        dinv[i] = rsqrtf((float)c + 1.0f);
        if (i == 0) row_ptr[0] = 0;
    }
}

// XCD-partitioned CSR scatter (round-8 lesson: unpartitioned random 4B
// scatter writes cost a 64B line writeback each -> 53 MB HBM write traffic
// as lines bounce between non-coherent per-XCD L2s). Default bid->XCD is
// round-robin (bid % 8), so block b handles edge chunk b>>3 but only dsts
// in range (b&7)*6250..+6250: each csr region is written from ONE XCD,
// lines stay L2-resident. Perf-only assumption; correctness holds anyway.
__global__ __launch_bounds__(256) void fill_kernel(const int* __restrict__ ei,
                                                   int* __restrict__ fill_ptr,
                                                   int* __restrict__ csr_src) {
    int r = blockIdx.x & (FILL_RANGES - 1);
    int e = (blockIdx.x >> 3) * 256 + threadIdx.x;
    if (e >= N_EDGES) return;
    int dst = ei[N_EDGES + e];
    int lo = r * RANGE_SIZE;
    if (dst >= lo && dst < lo + RANGE_SIZE) {
        int src = ei[e];
        int pos = atomicAdd(&fill_ptr[dst], 1);
        csr_src[pos] = src;
    }
}

// batch is sorted: find first node index with batch >= g, for g = 0..N_GRAPHS
__global__ void gstart_kernel(const int* __restrict__ batch, int* __restrict__ gstart) {
    int g = threadIdx.x;
    if (g <= N_GRAPHS) {
        int lo = 0, hi = N_NODES;
        while (lo < hi) {
            int mid = (lo + hi) >> 1;
            if (batch[mid] < g) lo = mid + 1; else hi = mid;
        }
        gstart[g] = lo;
    }
}

// hw2[row][col] = dinv[row] * sum_k h[row][k] * W[k][col]
// Tile kernel: block = 256 threads (4 waves), 64 rows per block.
// BOTH W and the 64-row h-tile staged in LDS via coalesced per-lane float4
// loads (round-6 lesson: wave-uniform global loads get scalarized ->
// lgkmcnt serialization with LDS reads). Wave computes 16 rows x 64 cols.
template <int K>
__global__ __launch_bounds__(256) void matmul_kernel(const float* __restrict__ h,
                                                     const float* __restrict__ W,
                                                     const float* __restrict__ dinv,
                                                     float* __restrict__ hw2) {
    constexpr int KC = K / 4;  // float4s per row
    __shared__ float sW[K * 64];
    __shared__ float sH[64 * K];
    int tid = threadIdx.x;
    int r0 = blockIdx.x * 64;

#pragma unroll 1
    for (int i = tid * 4; i < K * 64; i += 256 * 4)
        *(float4*)&sW[i] = *(const float4*)&W[i];
#pragma unroll 1
    for (int i = tid; i < 64 * KC; i += 256) {
        int rl = i / KC;
        int kc = i - rl * KC;
        int grow = min(r0 + rl, N_NODES - 1);  // clamp: safe read, write guarded
        *(float4*)&sH[rl * K + kc * 4] = *(const float4*)&h[(size_t)grow * K + kc * 4];
    }
    __syncthreads();

    int lane = tid & 63;
    int wid = tid >> 6;
    int rbase = wid * 16;

    float acc[16];
#pragma unroll
    for (int r = 0; r < 16; ++r) acc[r] = 0.f;

#pragma unroll 1
    for (int k = 0; k < K; k += 4) {
        float w0 = sW[(k + 0) * 64 + lane];
        float w1 = sW[(k + 1) * 64 + lane];
        float w2 = sW[(k + 2) * 64 + lane];
        float w3 = sW[(k + 3) * 64 + lane];
#pragma unroll
        for (int r = 0; r < 16; ++r) {
            float4 hh = *(const float4*)&sH[(rbase + r) * K + k];
            acc[r] += hh.x * w0 + hh.y * w1 + hh.z * w2 + hh.w * w3;
        }
    }
#pragma unroll
    for (int r = 0; r < 16; ++r) {
        int grow = r0 + rbase + r;
        if (grow < N_NODES) hw2[(size_t)grow * 64 + lane] = dinv[grow] * acc[r];
    }
}

// per node (one wave): edges processed 4 at a time.
// Edge indices pre-loaded coalesced (64 per chunk, one per lane), distributed
// via shfl with a WAVE-UNIFORM trip count (round-5 lesson: shfl from an
// exec-masked-off lane is undefined); only the accumulation is predicated.
__global__ __launch_bounds__(256) void agg_kernel(const float* __restrict__ hw2,
                                                  const int* __restrict__ row_ptr,
                                                  const int* __restrict__ csr_src,
                                                  const float* __restrict__ dinv,
                                                  const float* __restrict__ b,
                                                  float* __restrict__ hout) {
    int node = blockIdx.x * 4 + (threadIdx.x >> 6);
    int lane = threadIdx.x & 63;
    if (node >= N_NODES) return;
    int grp = lane >> 4;   // 0..3 : which edge of the 4-wide batch
    int gl  = lane & 15;   // 0..15: which float4 of the row
    int s = row_ptr[node], e = row_ptr[node + 1];

    float ax = 0.f, ay = 0.f, az = 0.f, aw = 0.f;
    for (int base = s; base < e; base += 64) {
        int nE = min(64, e - base);                          // wave-uniform
        int msrc = (lane < nE) ? csr_src[base + lane] : 0;   // coalesced
#pragma unroll 2
        for (int i = 0; i < nE; i += 4) {                    // uniform trip count
            int myi = i + grp;                               // <= 63 always
            int src = __shfl(msrc, myi, 64);                 // full-exec shfl
            if (myi < nE) {
                float4 v = *(const float4*)&hw2[(size_t)src * 64 + gl * 4];
                ax += v.x; ay += v.y; az += v.z; aw += v.w;
            }
        }
    }
    // sum the 4 groups' partials (dims are aligned across groups)
#pragma unroll
    for (int off = 16; off <= 32; off <<= 1) {
        ax += __shfl_xor(ax, off, 64);
        ay += __shfl_xor(ay, off, 64);
        az += __shfl_xor(az, off, 64);
        aw += __shfl_xor(aw, off, 64);
    }
    // self-loop term (hw2 pre-scaled by dinv[row])
    float4 self = *(const float4*)&hw2[(size_t)node * 64 + gl * 4];
    ax += self.x; ay += self.y; az += self.z; aw += self.w;

    float di = dinv[node];
    float4 bb = *(const float4*)&b[gl * 4];
    float vx = di * ax + bb.x;
    float vy = di * ay + bb.y;
    float vz = di * az + bb.z;
    float vw = di * aw + bb.w;

    float sq = vx * vx + vy * vy + vz * vz + vw * vw;
#pragma unroll
    for (int off = 1; off <= 8; off <<= 1) sq += __shfl_xor(sq, off, 64);
    float inv = 1.0f / fmaxf(sqrtf(sq), 1e-12f);

    if (grp == 0) {
        float4 r;
        r.x = fmaxf(vx * inv, 0.f);
        r.y = fmaxf(vy * inv, 0.f);
        r.z = fmaxf(vz * inv, 0.f);
        r.w = fmaxf(vw * inv, 0.f);
        *(float4*)&hout[(size_t)node * 64 + gl * 4] = r;
    }
}

// Phase-1 pooling: wave owns 16 consecutive nodes, lane = dim; batch sorted ->
// running (graph,sum,max) with atomic flush on transition. Post-ReLU values
// >= 0 so int-bit atomicMax is order-preserving and init-0 matches the
// empty-graph guard.
__global__ __launch_bounds__(256) void pool_partial_kernel(const float* __restrict__ h,
                                                           const int* __restrict__ batch,
                                                           float* __restrict__ gsum,
                                                           float* __restrict__ gmax) {
    int wid = threadIdx.x >> 6, lane = threadIdx.x & 63;
    int i0 = blockIdx.x * 64 + wid * 16;
    if (i0 >= N_NODES) return;
    int i1 = min(i0 + 16, N_NODES);
    int gcur = batch[i0];
    float sum = 0.f, mx = 0.f;
    for (int i = i0; i < i1; ++i) {
        int g = batch[i];
        if (g != gcur) {
            atomicAdd(&gsum[gcur * 64 + lane], sum);
            atomicMax((int*)&gmax[gcur * 64 + lane], __float_as_int(mx));
            sum = 0.f; mx = 0.f; gcur = g;
        }
        float v = h[(size_t)i * 64 + lane];
        sum += v;
        mx = fmaxf(mx, v);
    }
    atomicAdd(&gsum[gcur * 64 + lane], sum);
    atomicMax((int*)&gmax[gcur * 64 + lane], __float_as_int(mx));
}

// Phase-2: one block per graph; mean + concat + 128x32 linear.
__global__ __launch_bounds__(128) void linear_kernel(const float* __restrict__ gsum,
                                                     const float* __restrict__ gmax,
                                                     const int* __restrict__ gstart,
                                                     const float* __restrict__ Wl,
                                                     const float* __restrict__ bl,
                                                     float* __restrict__ out) {
    int g = blockIdx.x;
    __shared__ float pooled[128];
    int t = threadIdx.x;
    if (t < 64) {
        int cnt = gstart[g + 1] - gstart[g];
        pooled[t] = gsum[g * 64 + t] / fmaxf((float)cnt, 1.0f);
    } else {
        pooled[t] = gmax[g * 64 + (t - 64)];
    }
    __syncthreads();
    if (t < 32) {
        float acc = bl[t];
#pragma unroll 8
        for (int k = 0; k < 128; ++k) acc += pooled[k] * Wl[k * 32 + t];
        out[g * 32 + t] = acc;
    }
}

extern "C" void kernel_launch(void* const* d_in, const int* in_sizes, int n_in,
                              void* d_out, int out_size, void* d_ws, size_t ws_size,
                              hipStream_t stream) {
    const float* x        = (const float*)d_in[0];   // 50000 x 128
    const int*   ei       = (const int*)d_in[1];     // 2 x 800000
    const int*   batch    = (const int*)d_in[2];     // 50000
    const float* W1       = (const float*)d_in[3];   // 128 x 64
    const float* b1       = (const float*)d_in[4];
    const float* W2       = (const float*)d_in[5];   // 64 x 64
    const float* b2       = (const float*)d_in[6];
    const float* W3       = (const float*)d_in[7];   // 64 x 64
    const float* b3       = (const float*)d_in[8];
    const float* Wl       = (const float*)d_in[9];   // 128 x 32
    const float* bl       = (const float*)d_in[10];
    float* out = (float*)d_out;

    char* ws = (char*)d_ws;
    int*   cnt      = (int*)ws;                 ws += align256((size_t)N_NODES * 4);
    int*   incl     = (int*)ws;                 ws += align256((size_t)N_NODES * 4);
    int*   bsum     = (int*)ws;                 ws += align256((size_t)SCAN_NB * 4);
    int*   boff     = (int*)ws;                 ws += align256((size_t)SCAN_NB * 4);
    int*   row_ptr  = (int*)ws;                 ws += align256((size_t)(N_NODES + 1) * 4);
    int*   fill_ptr = (int*)ws;                 ws += align256((size_t)N_NODES * 4);
    float* dinv     = (float*)ws;               ws += align256((size_t)N_NODES * 4);
    int*   gstart   = (int*)ws;                 ws += align256((size_t)(N_GRAPHS + 1) * 4);
    float* gsum     = (float*)ws;               ws += align256((size_t)N_GRAPHS * 64 * 4);
    float* gmax     = (float*)ws;               ws += align256((size_t)N_GRAPHS * 64 * 4);
    int*   csr_src  = (int*)ws;                 ws += align256((size_t)N_EDGES * 4);
    float* hwb      = (float*)ws;               ws += align256((size_t)N_NODES * 64 * 4);
    float* h1       = (float*)ws;               ws += align256((size_t)N_NODES * 64 * 4);
    float* h2       = (float*)ws;               ws += align256((size_t)N_NODES * 64 * 4);

    hipLaunchKernelGGL(zero_i32, dim3((N_NODES + 255) / 256), dim3(256), 0, stream, cnt, N_NODES);
    // zero gsum+gmax (contiguous, 2*4096 floats)
    hipLaunchKernelGGL(zero_i32, dim3((2 * N_GRAPHS * 64 + 255) / 256), dim3(256), 0, stream,
                       (int*)gsum, 2 * N_GRAPHS * 64);
    hipLaunchKernelGGL(deg_kernel, dim3((N_EDGES + 255) / 256), dim3(256), 0, stream, ei, cnt);
    hipLaunchKernelGGL(scan_a, dim3(SCAN_NB), dim3(256), 0, stream, cnt, incl, bsum);
    hipLaunchKernelGGL(scan_b, dim3(1), dim3(256), 0, stream, bsum, boff);
    hipLaunchKernelGGL(scan_c, dim3(SCAN_NB), dim3(256), 0, stream,
                       cnt, incl, boff, row_ptr, fill_ptr, dinv);
    hipLaunchKernelGGL(fill_kernel,
                       dim3(FILL_RANGES * ((N_EDGES + 255) / 256)), dim3(256), 0, stream,
                       ei, fill_ptr, csr_src);
    hipLaunchKernelGGL(gstart_kernel, dim3(1), dim3(128), 0, stream, batch, gstart);

    const int mm_grid = (N_NODES + 63) / 64;
    const int agg_grid = (N_NODES + 3) / 4;  // 4 waves per block, wave per node

    // layer 1: x(128) @ W1 -> hw2 (dinv-scaled); agg -> h1
    hipLaunchKernelGGL((matmul_kernel<128>), dim3(mm_grid), dim3(256), 0, stream, x, W1, dinv, hwb);
    hipLaunchKernelGGL(agg_kernel, dim3(agg_grid), dim3(256), 0, stream,
                       hwb, row_ptr, csr_src, dinv, b1, h1);
    // layer 2
    hipLaunchKernelGGL((matmul_kernel<64>), dim3(mm_grid), dim3(256), 0, stream, h1, W2, dinv, hwb);
    hipLaunchKernelGGL(agg_kernel, dim3(agg_grid), dim3(256), 0, stream,
                       hwb, row_ptr, csr_src, dinv, b2, h2);
    // layer 3
    hipLaunchKernelGGL((matmul_kernel<64>), dim3(mm_grid), dim3(256), 0, stream, h2, W3, dinv, hwb);
    hipLaunchKernelGGL(agg_kernel, dim3(agg_grid), dim3(256), 0, stream,
                       hwb, row_ptr, csr_src, dinv, b3, h1);

    // two-phase pooling + final linear
    hipLaunchKernelGGL(pool_partial_kernel, dim3((N_NODES + 63) / 64), dim3(256), 0, stream,
                       h1, batch, gsum, gmax);
    hipLaunchKernelGGL(linear_kernel, dim3(N_GRAPHS), dim3(128), 0, stream,
                       gsum, gmax, gstart, Wl, bl, out);
}

// Round 10
// 273.939 us; speedup vs baseline: 1.4749x; 1.0726x over previous
//
#include <hip/hip_runtime.h>
#include <hip/hip_bf16.h>

#define N_NODES 50000
#define N_EDGES 800000
#define N_GRAPHS 64
#define HID 64
#define SCAN_NB 196  // ceil(50000/256)
#define FILL_RANGES 8
#define RANGE_SIZE ((N_NODES + FILL_RANGES - 1) / FILL_RANGES)  // 6250

static inline size_t align256(size_t x) { return (x + 255) & ~(size_t)255; }

// bf16 helpers (bit-level, RNE) -- storage-only compression of hw2.
__device__ __forceinline__ unsigned short f2bf(float f) {
    unsigned int u = __float_as_uint(f);
    unsigned int r = (u + 0x7fffu + ((u >> 16) & 1u)) >> 16;
    return (unsigned short)r;
}
__device__ __forceinline__ float bf2f(unsigned short h) {
    return __uint_as_float(((unsigned int)h) << 16);
}

__global__ void zero_i32(int* __restrict__ p, int n) {
    int i = blockIdx.x * blockDim.x + threadIdx.x;
    if (i < n) p[i] = 0;
}

// count incoming edges per destination node
__global__ void deg_kernel(const int* __restrict__ ei, int* __restrict__ cnt) {
    int e = blockIdx.x * blockDim.x + threadIdx.x;
    if (e < N_EDGES) atomicAdd(&cnt[ei[N_EDGES + e]], 1);
}

// phase A: per-block (256-wide) inclusive scan of cnt; block totals to bsum
__global__ __launch_bounds__(256) void scan_a(const int* __restrict__ cnt,
                                              int* __restrict__ incl,
                                              int* __restrict__ bsum) {
    __shared__ int sd[256];
    int t = threadIdx.x;
    int i = blockIdx.x * 256 + t;
    int v = (i < N_NODES) ? cnt[i] : 0;
    sd[t] = v;
    __syncthreads();
    for (int off = 1; off < 256; off <<= 1) {
        int u = (t >= off) ? sd[t - off] : 0;
        __syncthreads();
        sd[t] += u;
        __syncthreads();
    }
    if (i < N_NODES) incl[i] = sd[t];
    if (t == 255) bsum[blockIdx.x] = sd[255];
}

// phase B: single block, exclusive scan of the 196 block sums
__global__ __launch_bounds__(256) void scan_b(const int* __restrict__ bsum,
                                              int* __restrict__ boff) {
    __shared__ int sd[256];
    int t = threadIdx.x;
    int v = (t < SCAN_NB) ? bsum[t] : 0;
    sd[t] = v;
    __syncthreads();
    for (int off = 1; off < 256; off <<= 1) {
        int u = (t >= off) ? sd[t - off] : 0;
        __syncthreads();
        sd[t] += u;
        __syncthreads();
    }
    if (t < SCAN_NB) boff[t] = sd[t] - v;  // exclusive
}

// phase C: writeback row_ptr / fill_ptr / dinv
__global__ void scan_c(const int* __restrict__ cnt, const int* __restrict__ incl,
                       const int* __restrict__ boff, int* __restrict__ row_ptr,
                       int* __restrict__ fill_ptr, float* __restrict__ dinv) {
    int i = blockIdx.x * blockDim.x + threadIdx.x;
    if (i < N_NODES) {
        int c = cnt[i];
        int run = boff[i >> 8] + incl[i];  // inclusive prefix over all nodes
        row_ptr[i + 1] = run;
        fill_ptr[i] = run - c;             // bucket start
        dinv[i] = rsqrtf((float)c + 1.0f);
        if (i == 0) row_ptr[0] = 0;
    }
}

// XCD-partitioned CSR scatter (round-8 lesson: unpartitioned random 4B
// scatter writes cost a 64B line writeback each; partition dst ranges so
// each csr region is written from one XCD and lines stay L2-resident).
__global__ __launch_bounds__(256) void fill_kernel(const int* __restrict__ ei,
                                                   int* __restrict__ fill_ptr,
                                                   int* __restrict__ csr_src) {
    int r = blockIdx.x & (FILL_RANGES - 1);
    int e = (blockIdx.x >> 3) * 256 + threadIdx.x;
    if (e >= N_EDGES) return;
    int dst = ei[N_EDGES + e];
    int lo = r * RANGE_SIZE;
    if (dst >= lo && dst < lo + RANGE_SIZE) {
        int src = ei[e];
        int pos = atomicAdd(&fill_ptr[dst], 1);
        csr_src[pos] = src;
    }
}

// batch is sorted: find first node index with batch >= g, for g = 0..N_GRAPHS
__global__ void gstart_kernel(const int* __restrict__ batch, int* __restrict__ gstart) {
    int g = threadIdx.x;
    if (g <= N_GRAPHS) {
        int lo = 0, hi = N_NODES;
        while (lo < hi) {
            int mid = (lo + hi) >> 1;
            if (batch[mid] < g) lo = mid + 1; else hi = mid;
        }
        gstart[g] = lo;
    }
}

// hw2[row][col] = bf16( dinv[row] * sum_k h[row][k] * W[k][col] )
// 256 threads = 4 waves, 64 rows per block; wave computes 16 rows x 64 cols.
// W + a 64-row h-tile in LDS via coalesced float4 loads (round-6 lesson:
// uniform global loads scalarize onto lgkmcnt and serialize with LDS).
// Round-9 lesson: inner loop is LDS-read-throughput-bound and 64KB LDS caps
// occupancy at 2 blocks/CU -> stage sH in 64-k halves (48KB for K=128,
// 32KB for K=64) to get 3/5 blocks per CU.
template <int K>
__global__ __launch_bounds__(256) void matmul_kernel(const float* __restrict__ h,
                                                     const float* __restrict__ W,
                                                     const float* __restrict__ dinv,
                                                     unsigned short* __restrict__ hw2) {
    constexpr int NHALF = K / 64;
    __shared__ float sW[K * 64];
    __shared__ float sH[64 * 64];
    int tid = threadIdx.x;
    int r0 = blockIdx.x * 64;

#pragma unroll 1
    for (int i = tid * 4; i < K * 64; i += 256 * 4)
        *(float4*)&sW[i] = *(const float4*)&W[i];

    int lane = tid & 63;
    int wid = tid >> 6;
    int rbase = wid * 16;

    float acc[16];
#pragma unroll
    for (int r = 0; r < 16; ++r) acc[r] = 0.f;

#pragma unroll 1
    for (int half = 0; half < NHALF; ++half) {
        // stage 64 rows x 64 ks of h (16 KB)
#pragma unroll 1
        for (int i = tid; i < 64 * 16; i += 256) {
            int rl = i >> 4;          // local row
            int kc = i & 15;          // float4 index within the half
            int grow = min(r0 + rl, N_NODES - 1);  // clamp; write guarded below
            *(float4*)&sH[rl * 64 + kc * 4] =
                *(const float4*)&h[(size_t)grow * K + half * 64 + kc * 4];
        }
        __syncthreads();
#pragma unroll 1
        for (int kl = 0; kl < 64; kl += 4) {
            int k = half * 64 + kl;
            float w0 = sW[(k + 0) * 64 + lane];
            float w1 = sW[(k + 1) * 64 + lane];
            float w2 = sW[(k + 2) * 64 + lane];
            float w3 = sW[(k + 3) * 64 + lane];
#pragma unroll
            for (int r = 0; r < 16; ++r) {
                float4 hh = *(const float4*)&sH[(rbase + r) * 64 + kl];
                acc[r] += hh.x * w0 + hh.y * w1 + hh.z * w2 + hh.w * w3;
            }
        }
        __syncthreads();
    }
#pragma unroll
    for (int r = 0; r < 16; ++r) {
        int grow = r0 + rbase + r;
        if (grow < N_NODES) hw2[(size_t)grow * 64 + lane] = f2bf(dinv[grow] * acc[r]);
    }
}

// per node (one wave): edges processed 4 at a time; hw2 rows are bf16 (128B)
// so each of the 16 lanes in a group reads 8B (4 dims). Edge indices
// pre-loaded coalesced and distributed via shfl with WAVE-UNIFORM trip count
// (round-5 lesson); only the accumulation is predicated.
__global__ __launch_bounds__(256) void agg_kernel(const unsigned short* __restrict__ hw2,
                                                  const int* __restrict__ row_ptr,
                                                  const int* __restrict__ csr_src,
                                                  const float* __restrict__ dinv,
                                                  const float* __restrict__ b,
                                                  float* __restrict__ hout) {
    int node = blockIdx.x * 4 + (threadIdx.x >> 6);
    int lane = threadIdx.x & 63;
    if (node >= N_NODES) return;
    int grp = lane >> 4;   // 0..3 : which edge of the 4-wide batch
    int gl  = lane & 15;   // 0..15: which 4-dim slice of the row
    int s = row_ptr[node], e = row_ptr[node + 1];

    float ax = 0.f, ay = 0.f, az = 0.f, aw = 0.f;
    for (int base = s; base < e; base += 64) {
        int nE = min(64, e - base);                          // wave-uniform
        int msrc = (lane < nE) ? csr_src[base + lane] : 0;   // coalesced
#pragma unroll 2
        for (int i = 0; i < nE; i += 4) {                    // uniform trip count
            int myi = i + grp;                               // <= 63 always
            int src = __shfl(msrc, myi, 64);                 // full-exec shfl
            if (myi < nE) {
                ushort4 v = *(const ushort4*)&hw2[(size_t)src * 64 + gl * 4];
                ax += bf2f(v.x); ay += bf2f(v.y); az += bf2f(v.z); aw += bf2f(v.w);
            }
        }
    }
    // sum the 4 groups' partials (dims are aligned across groups)
#pragma unroll
    for (int off = 16; off <= 32; off <<= 1) {
        ax += __shfl_xor(ax, off, 64);
        ay += __shfl_xor(ay, off, 64);
        az += __shfl_xor(az, off, 64);
        aw += __shfl_xor(aw, off, 64);
    }
    // self-loop term (hw2 pre-scaled by dinv[row])
    ushort4 sv = *(const ushort4*)&hw2[(size_t)node * 64 + gl * 4];
    ax += bf2f(sv.x); ay += bf2f(sv.y); az += bf2f(sv.z); aw += bf2f(sv.w);

    float di = dinv[node];
    float4 bb = *(const float4*)&b[gl * 4];
    float vx = di * ax + bb.x;
    float vy = di * ay + bb.y;
    float vz = di * az + bb.z;
    float vw = di * aw + bb.w;

    float sq = vx * vx + vy * vy + vz * vz + vw * vw;
#pragma unroll
    for (int off = 1; off <= 8; off <<= 1) sq += __shfl_xor(sq, off, 64);
    float inv = 1.0f / fmaxf(sqrtf(sq), 1e-12f);

    if (grp == 0) {
        float4 r;
        r.x = fmaxf(vx * inv, 0.f);
        r.y = fmaxf(vy * inv, 0.f);
        r.z = fmaxf(vz * inv, 0.f);
        r.w = fmaxf(vw * inv, 0.f);
        *(float4*)&hout[(size_t)node * 64 + gl * 4] = r;
    }
}

// Phase-1 pooling: wave owns 16 consecutive nodes, lane = dim; batch sorted ->
// running (graph,sum,max) with atomic flush on transition. Post-ReLU values
// >= 0 so int-bit atomicMax is order-preserving and init-0 matches the
// empty-graph guard.
__global__ __launch_bounds__(256) void pool_partial_kernel(const float* __restrict__ h,
                                                           const int* __restrict__ batch,
                                                           float* __restrict__ gsum,
                                                           float* __restrict__ gmax) {
    int wid = threadIdx.x >> 6, lane = threadIdx.x & 63;
    int i0 = blockIdx.x * 64 + wid * 16;
    if (i0 >= N_NODES) return;
    int i1 = min(i0 + 16, N_NODES);
    int gcur = batch[i0];
    float sum = 0.f, mx = 0.f;
    for (int i = i0; i < i1; ++i) {
        int g = batch[i];
        if (g != gcur) {
            atomicAdd(&gsum[gcur * 64 + lane], sum);
            atomicMax((int*)&gmax[gcur * 64 + lane], __float_as_int(mx));
            sum = 0.f; mx = 0.f; gcur = g;
        }
        float v = h[(size_t)i * 64 + lane];
        sum += v;
        mx = fmaxf(mx, v);
    }
    atomicAdd(&gsum[gcur * 64 + lane], sum);
    atomicMax((int*)&gmax[gcur * 64 + lane], __float_as_int(mx));
}

// Phase-2: one block per graph; mean + concat + 128x32 linear.
__global__ __launch_bounds__(128) void linear_kernel(const float* __restrict__ gsum,
                                                     const float* __restrict__ gmax,
                                                     const int* __restrict__ gstart,
                                                     const float* __restrict__ Wl,
                                                     const float* __restrict__ bl,
                                                     float* __restrict__ out) {
    int g = blockIdx.x;
    __shared__ float pooled[128];
    int t = threadIdx.x;
    if (t < 64) {
        int cnt = gstart[g + 1] - gstart[g];
        pooled[t] = gsum[g * 64 + t] / fmaxf((float)cnt, 1.0f);
    } else {
        pooled[t] = gmax[g * 64 + (t - 64)];
    }
    __syncthreads();
    if (t < 32) {
        float acc = bl[t];
#pragma unroll 8
        for (int k = 0; k < 128; ++k) acc += pooled[k] * Wl[k * 32 + t];
        out[g * 32 + t] = acc;
    }
}

extern "C" void kernel_launch(void* const* d_in, const int* in_sizes, int n_in,
                              void* d_out, int out_size, void* d_ws, size_t ws_size,
                              hipStream_t stream) {
    const float* x        = (const float*)d_in[0];   // 50000 x 128
    const int*   ei       = (const int*)d_in[1];     // 2 x 800000
    const int*   batch    = (const int*)d_in[2];     // 50000
    const float* W1       = (const float*)d_in[3];   // 128 x 64
    const float* b1       = (const float*)d_in[4];
    const float* W2       = (const float*)d_in[5];   // 64 x 64
    const float* b2       = (const float*)d_in[6];
    const float* W3       = (const float*)d_in[7];   // 64 x 64
    const float* b3       = (const float*)d_in[8];
    const float* Wl       = (const float*)d_in[9];   // 128 x 32
    const float* bl       = (const float*)d_in[10];
    float* out = (float*)d_out;

    char* ws = (char*)d_ws;
    int*   cnt      = (int*)ws;                 ws += align256((size_t)N_NODES * 4);
    int*   incl     = (int*)ws;                 ws += align256((size_t)N_NODES * 4);
    int*   bsum     = (int*)ws;                 ws += align256((size_t)SCAN_NB * 4);
    int*   boff     = (int*)ws;                 ws += align256((size_t)SCAN_NB * 4);
    int*   row_ptr  = (int*)ws;                 ws += align256((size_t)(N_NODES + 1) * 4);
    int*   fill_ptr = (int*)ws;                 ws += align256((size_t)N_NODES * 4);
    float* dinv     = (float*)ws;               ws += align256((size_t)N_NODES * 4);
    int*   gstart   = (int*)ws;                 ws += align256((size_t)(N_GRAPHS + 1) * 4);
    float* gsum     = (float*)ws;               ws += align256((size_t)N_GRAPHS * 64 * 4);
    float* gmax     = (float*)ws;               ws += align256((size_t)N_GRAPHS * 64 * 4);
    int*   csr_src  = (int*)ws;                 ws += align256((size_t)N_EDGES * 4);
    unsigned short* hwb = (unsigned short*)ws;  ws += align256((size_t)N_NODES * 64 * 2);
    float* h1       = (float*)ws;               ws += align256((size_t)N_NODES * 64 * 4);
    float* h2       = (float*)ws;               ws += align256((size_t)N_NODES * 64 * 4);

    hipLaunchKernelGGL(zero_i32, dim3((N_NODES + 255) / 256), dim3(256), 0, stream, cnt, N_NODES);
    // zero gsum+gmax (contiguous, 2*4096 floats)
    hipLaunchKernelGGL(zero_i32, dim3((2 * N_GRAPHS * 64 + 255) / 256), dim3(256), 0, stream,
                       (int*)gsum, 2 * N_GRAPHS * 64);
    hipLaunchKernelGGL(deg_kernel, dim3((N_EDGES + 255) / 256), dim3(256), 0, stream, ei, cnt);
    hipLaunchKernelGGL(scan_a, dim3(SCAN_NB), dim3(256), 0, stream, cnt, incl, bsum);
    hipLaunchKernelGGL(scan_b, dim3(1), dim3(256), 0, stream, bsum, boff);
    hipLaunchKernelGGL(scan_c, dim3(SCAN_NB), dim3(256), 0, stream,
                       cnt, incl, boff, row_ptr, fill_ptr, dinv);
    hipLaunchKernelGGL(fill_kernel,
                       dim3(FILL_RANGES * ((N_EDGES + 255) / 256)), dim3(256), 0, stream,
                       ei, fill_ptr, csr_src);
    hipLaunchKernelGGL(gstart_kernel, dim3(1), dim3(128), 0, stream, batch, gstart);

    const int mm_grid = (N_NODES + 63) / 64;
    const int agg_grid = (N_NODES + 3) / 4;  // 4 waves per block, wave per node

    // layer 1: x(128) @ W1 -> hw2 (dinv-scaled, bf16); agg -> h1
    hipLaunchKernelGGL((matmul_kernel<128>), dim3(mm_grid), dim3(256), 0, stream, x, W1, dinv, hwb);
    hipLaunchKernelGGL(agg_kernel, dim3(agg_grid), dim3(256), 0, stream,
                       hwb, row_ptr, csr_src, dinv, b1, h1);
    // layer 2
    hipLaunchKernelGGL((matmul_kernel<64>), dim3(mm_grid), dim3(256), 0, stream, h1, W2, dinv, hwb);
    hipLaunchKernelGGL(agg_kernel, dim3(agg_grid), dim3(256), 0, stream,
                       hwb, row_ptr, csr_src, dinv, b2, h2);
    // layer 3
    hipLaunchKernelGGL((matmul_kernel<64>), dim3(mm_grid), dim3(256), 0, stream, h2, W3, dinv, hwb);
    hipLaunchKernelGGL(agg_kernel, dim3(agg_grid), dim3(256), 0, stream,
                       hwb, row_ptr, csr_src, dinv, b3, h1);

    // two-phase pooling + final linear
    hipLaunchKernelGGL(pool_partial_kernel, dim3((N_NODES + 63) / 64), dim3(256), 0, stream,
                       h1, batch, gsum, gmax);
    hipLaunchKernelGGL(linear_kernel, dim3(N_GRAPHS), dim3(128), 0, stream,
                       gsum, gmax, gstart, Wl, bl, out);
}

// Round 11
// 223.641 us; speedup vs baseline: 1.8066x; 1.2249x over previous
//
#include <hip/hip_runtime.h>
#include <hip/hip_bf16.h>

#define N_NODES 50000
#define N_EDGES 800000
#define N_GRAPHS 64
#define HID 64
#define SCAN_NB 196  // ceil(50000/256)
#define FILL_RANGES 8
#define RANGE_SIZE ((N_NODES + FILL_RANGES - 1) / FILL_RANGES)  // 6250

static inline size_t align256(size_t x) { return (x + 255) & ~(size_t)255; }

typedef __attribute__((ext_vector_type(8))) short short8v;
typedef __attribute__((ext_vector_type(4))) float f32x4;

// bf16 helpers (bit-level, RNE) -- storage compression + MFMA input prep.
__device__ __forceinline__ unsigned short f2bf(float f) {
    unsigned int u = __float_as_uint(f);
    unsigned int r = (u + 0x7fffu + ((u >> 16) & 1u)) >> 16;
    return (unsigned short)r;
}
__device__ __forceinline__ float bf2f(unsigned short h) {
    return __uint_as_float(((unsigned int)h) << 16);
}

__global__ void zero_i32(int* __restrict__ p, int n) {
    int i = blockIdx.x * blockDim.x + threadIdx.x;
    if (i < n) p[i] = 0;
}

// count incoming edges per destination node
__global__ void deg_kernel(const int* __restrict__ ei, int* __restrict__ cnt) {
    int e = blockIdx.x * blockDim.x + threadIdx.x;
    if (e < N_EDGES) atomicAdd(&cnt[ei[N_EDGES + e]], 1);
}

// phase A: per-block (256-wide) inclusive scan of cnt; block totals to bsum
__global__ __launch_bounds__(256) void scan_a(const int* __restrict__ cnt,
                                              int* __restrict__ incl,
                                              int* __restrict__ bsum) {
    __shared__ int sd[256];
    int t = threadIdx.x;
    int i = blockIdx.x * 256 + t;
    int v = (i < N_NODES) ? cnt[i] : 0;
    sd[t] = v;
    __syncthreads();
    for (int off = 1; off < 256; off <<= 1) {
        int u = (t >= off) ? sd[t - off] : 0;
        __syncthreads();
        sd[t] += u;
        __syncthreads();
    }
    if (i < N_NODES) incl[i] = sd[t];
    if (t == 255) bsum[blockIdx.x] = sd[255];
}

// phase B: single block, exclusive scan of the 196 block sums
__global__ __launch_bounds__(256) void scan_b(const int* __restrict__ bsum,
                                              int* __restrict__ boff) {
    __shared__ int sd[256];
    int t = threadIdx.x;
    int v = (t < SCAN_NB) ? bsum[t] : 0;
    sd[t] = v;
    __syncthreads();
    for (int off = 1; off < 256; off <<= 1) {
        int u = (t >= off) ? sd[t - off] : 0;
        __syncthreads();
        sd[t] += u;
        __syncthreads();
    }
    if (t < SCAN_NB) boff[t] = sd[t] - v;  // exclusive
}

// phase C: writeback row_ptr / fill_ptr / dinv
__global__ void scan_c(const int* __restrict__ cnt, const int* __restrict__ incl,
                       const int* __restrict__ boff, int* __restrict__ row_ptr,
                       int* __restrict__ fill_ptr, float* __restrict__ dinv) {
    int i = blockIdx.x * blockDim.x + threadIdx.x;
    if (i < N_NODES) {
        int c = cnt[i];
        int run = boff[i >> 8] + incl[i];  // inclusive prefix over all nodes
        row_ptr[i + 1] = run;
        fill_ptr[i] = run - c;             // bucket start
        dinv[i] = rsqrtf((float)c + 1.0f);
        if (i == 0) row_ptr[0] = 0;
    }
}

// XCD-partitioned CSR scatter (round-8 lesson: unpartitioned random 4B
// scatter writes cost a 64B line writeback each; partition dst ranges so
// each csr region is written from one XCD and lines stay L2-resident).
__global__ __launch_bounds__(256) void fill_kernel(const int* __restrict__ ei,
                                                   int* __restrict__ fill_ptr,
                                                   int* __restrict__ csr_src) {
    int r = blockIdx.x & (FILL_RANGES - 1);
    int e = (blockIdx.x >> 3) * 256 + threadIdx.x;
    if (e >= N_EDGES) return;
    int dst = ei[N_EDGES + e];
    int lo = r * RANGE_SIZE;
    if (dst >= lo && dst < lo + RANGE_SIZE) {
        int src = ei[e];
        int pos = atomicAdd(&fill_ptr[dst], 1);
        csr_src[pos] = src;
    }
}

// batch is sorted: find first node index with batch >= g, for g = 0..N_GRAPHS
__global__ void gstart_kernel(const int* __restrict__ batch, int* __restrict__ gstart) {
    int g = threadIdx.x;
    if (g <= N_GRAPHS) {
        int lo = 0, hi = N_NODES;
        while (lo < hi) {
            int mid = (lo + hi) >> 1;
            if (batch[mid] < g) lo = mid + 1; else hi = mid;
        }
        gstart[g] = lo;
    }
}

// MFMA matmul: hw2[row][col] = bf16( dinv[row] * sum_k h[row][k]*W[k][col] )
// 4 waves x 16 rows = 64 rows/block. 3-term hi/lo bf16 split keeps error at
// the bf16^2 level (~1.6e-5): AhiBhi + AloBhi + AhiBlo.
// W staged in LDS pre-swizzled into FRAGMENT order (lane-indexed 16B ->
// conflict-free ds_read_b128). A-frags: per-lane global loads (L3-resident)
// + RNE converts. Layouts (m89-verified D): A[l&15][8*(l>>4)+j],
// B[8*(l>>4)+j][l&15], D row=(l>>4)*4+j, col=l&15.
template <int K>
__global__ __launch_bounds__(256) void mfma_matmul(const float* __restrict__ h,
                                                   const float* __restrict__ W,
                                                   const float* __restrict__ dinv,
                                                   unsigned short* __restrict__ hw2) {
    constexpr int NSTEP = K / 32;
    __shared__ unsigned short sWH[NSTEP * 4 * 64 * 8];
    __shared__ unsigned short sWL[NSTEP * 4 * 64 * 8];
    int tid = threadIdx.x;
    int r0 = blockIdx.x * 64;

    // stage W fragments (bf16 hi/lo), fragment-order layout
#pragma unroll 1
    for (int ent = tid; ent < NSTEP * 4 * 64; ent += 256) {
        int lane_e = ent & 63;
        int c = (ent >> 6) & 3;
        int step = ent >> 8;
        int kb = step * 32 + (lane_e >> 4) * 8;
        int n = c * 16 + (lane_e & 15);
#pragma unroll
        for (int j = 0; j < 8; ++j) {
            float f = W[(kb + j) * 64 + n];
            unsigned short hi = f2bf(f);
            sWH[ent * 8 + j] = hi;
            sWL[ent * 8 + j] = f2bf(f - bf2f(hi));
        }
    }
    __syncthreads();

    int lane = tid & 63;
    int wid = tid >> 6;
    int arow = min(r0 + wid * 16 + (lane & 15), N_NODES - 1);  // clamp; write guarded
    const float* ap = h + (size_t)arow * K;
    int klane = (lane >> 4) * 8;

    f32x4 acc[4];
#pragma unroll
    for (int c = 0; c < 4; ++c) acc[c] = (f32x4){0.f, 0.f, 0.f, 0.f};

#pragma unroll 1
    for (int step = 0; step < NSTEP; ++step) {
        int kb = step * 32 + klane;
        float4 f0 = *(const float4*)&ap[kb];
        float4 f1 = *(const float4*)&ap[kb + 4];
        float fv[8] = {f0.x, f0.y, f0.z, f0.w, f1.x, f1.y, f1.z, f1.w};
        short8v ahi, alo;
#pragma unroll
        for (int j = 0; j < 8; ++j) {
            unsigned short hi = f2bf(fv[j]);
            ahi[j] = (short)hi;
            alo[j] = (short)f2bf(fv[j] - bf2f(hi));
        }
#pragma unroll
        for (int c = 0; c < 4; ++c) {
            short8v bh = *(const short8v*)&sWH[((step * 4 + c) * 64 + lane) * 8];
            short8v bl = *(const short8v*)&sWL[((step * 4 + c) * 64 + lane) * 8];
            acc[c] = __builtin_amdgcn_mfma_f32_16x16x32_bf16(ahi, bh, acc[c], 0, 0, 0);
            acc[c] = __builtin_amdgcn_mfma_f32_16x16x32_bf16(alo, bh, acc[c], 0, 0, 0);
            acc[c] = __builtin_amdgcn_mfma_f32_16x16x32_bf16(ahi, bl, acc[c], 0, 0, 0);
        }
    }

    int rb = r0 + wid * 16 + (lane >> 4) * 4;
#pragma unroll
    for (int j = 0; j < 4; ++j) {
        int row = rb + j;
        if (row < N_NODES) {
            float dv = dinv[row];
#pragma unroll
            for (int c = 0; c < 4; ++c) {
                hw2[(size_t)row * 64 + c * 16 + (lane & 15)] = f2bf(dv * acc[c][j]);
            }
        }
    }
}

// per node (one wave): edges processed 4 at a time; hw2 rows are bf16 (128B)
// so each of the 16 lanes in a group reads 8B (4 dims). Edge indices
// pre-loaded coalesced and distributed via shfl with WAVE-UNIFORM trip count
// (round-5 lesson); only the accumulation is predicated.
__global__ __launch_bounds__(256) void agg_kernel(const unsigned short* __restrict__ hw2,
                                                  const int* __restrict__ row_ptr,
                                                  const int* __restrict__ csr_src,
                                                  const float* __restrict__ dinv,
                                                  const float* __restrict__ b,
                                                  float* __restrict__ hout) {
    int node = blockIdx.x * 4 + (threadIdx.x >> 6);
    int lane = threadIdx.x & 63;
    if (node >= N_NODES) return;
    int grp = lane >> 4;   // 0..3 : which edge of the 4-wide batch
    int gl  = lane & 15;   // 0..15: which 4-dim slice of the row
    int s = row_ptr[node], e = row_ptr[node + 1];

    float ax = 0.f, ay = 0.f, az = 0.f, aw = 0.f;
    for (int base = s; base < e; base += 64) {
        int nE = min(64, e - base);                          // wave-uniform
        int msrc = (lane < nE) ? csr_src[base + lane] : 0;   // coalesced
#pragma unroll 2
        for (int i = 0; i < nE; i += 4) {                    // uniform trip count
            int myi = i + grp;                               // <= 63 always
            int src = __shfl(msrc, myi, 64);                 // full-exec shfl
            if (myi < nE) {
                ushort4 v = *(const ushort4*)&hw2[(size_t)src * 64 + gl * 4];
                ax += bf2f(v.x); ay += bf2f(v.y); az += bf2f(v.z); aw += bf2f(v.w);
            }
        }
    }
    // sum the 4 groups' partials (dims are aligned across groups)
#pragma unroll
    for (int off = 16; off <= 32; off <<= 1) {
        ax += __shfl_xor(ax, off, 64);
        ay += __shfl_xor(ay, off, 64);
        az += __shfl_xor(az, off, 64);
        aw += __shfl_xor(aw, off, 64);
    }
    // self-loop term (hw2 pre-scaled by dinv[row])
    ushort4 sv = *(const ushort4*)&hw2[(size_t)node * 64 + gl * 4];
    ax += bf2f(sv.x); ay += bf2f(sv.y); az += bf2f(sv.z); aw += bf2f(sv.w);

    float di = dinv[node];
    float4 bb = *(const float4*)&b[gl * 4];
    float vx = di * ax + bb.x;
    float vy = di * ay + bb.y;
    float vz = di * az + bb.z;
    float vw = di * aw + bb.w;

    float sq = vx * vx + vy * vy + vz * vz + vw * vw;
#pragma unroll
    for (int off = 1; off <= 8; off <<= 1) sq += __shfl_xor(sq, off, 64);
    float inv = 1.0f / fmaxf(sqrtf(sq), 1e-12f);

    if (grp == 0) {
        float4 r;
        r.x = fmaxf(vx * inv, 0.f);
        r.y = fmaxf(vy * inv, 0.f);
        r.z = fmaxf(vz * inv, 0.f);
        r.w = fmaxf(vw * inv, 0.f);
        *(float4*)&hout[(size_t)node * 64 + gl * 4] = r;
    }
}

// Phase-1 pooling: wave owns 16 consecutive nodes, lane = dim; batch sorted ->
// running (graph,sum,max) with atomic flush on transition. Post-ReLU values
// >= 0 so int-bit atomicMax is order-preserving and init-0 matches the
// empty-graph guard.
__global__ __launch_bounds__(256) void pool_partial_kernel(const float* __restrict__ h,
                                                           const int* __restrict__ batch,
                                                           float* __restrict__ gsum,
                                                           float* __restrict__ gmax) {
    int wid = threadIdx.x >> 6, lane = threadIdx.x & 63;
    int i0 = blockIdx.x * 64 + wid * 16;
    if (i0 >= N_NODES) return;
    int i1 = min(i0 + 16, N_NODES);
    int gcur = batch[i0];
    float sum = 0.f, mx = 0.f;
    for (int i = i0; i < i1; ++i) {
        int g = batch[i];
        if (g != gcur) {
            atomicAdd(&gsum[gcur * 64 + lane], sum);
            atomicMax((int*)&gmax[gcur * 64 + lane], __float_as_int(mx));
            sum = 0.f; mx = 0.f; gcur = g;
        }
        float v = h[(size_t)i * 64 + lane];
        sum += v;
        mx = fmaxf(mx, v);
    }
    atomicAdd(&gsum[gcur * 64 + lane], sum);
    atomicMax((int*)&gmax[gcur * 64 + lane], __float_as_int(mx));
}

// Phase-2: one block per graph; mean + concat + 128x32 linear.
__global__ __launch_bounds__(128) void linear_kernel(const float* __restrict__ gsum,
                                                     const float* __restrict__ gmax,
                                                     const int* __restrict__ gstart,
                                                     const float* __restrict__ Wl,
                                                     const float* __restrict__ bl,
                                                     float* __restrict__ out) {
    int g = blockIdx.x;
    __shared__ float pooled[128];
    int t = threadIdx.x;
    if (t < 64) {
        int cnt = gstart[g + 1] - gstart[g];
        pooled[t] = gsum[g * 64 + t] / fmaxf((float)cnt, 1.0f);
    } else {
        pooled[t] = gmax[g * 64 + (t - 64)];
    }
    __syncthreads();
    if (t < 32) {
        float acc = bl[t];
#pragma unroll 8
        for (int k = 0; k < 128; ++k) acc += pooled[k] * Wl[k * 32 + t];
        out[g * 32 + t] = acc;
    }
}

extern "C" void kernel_launch(void* const* d_in, const int* in_sizes, int n_in,
                              void* d_out, int out_size, void* d_ws, size_t ws_size,
                              hipStream_t stream) {
    const float* x        = (const float*)d_in[0];   // 50000 x 128
    const int*   ei       = (const int*)d_in[1];     // 2 x 800000
    const int*   batch    = (const int*)d_in[2];     // 50000
    const float* W1       = (const float*)d_in[3];   // 128 x 64
    const float* b1       = (const float*)d_in[4];
    const float* W2       = (const float*)d_in[5];   // 64 x 64
    const float* b2       = (const float*)d_in[6];
    const float* W3       = (const float*)d_in[7];   // 64 x 64
    const float* b3       = (const float*)d_in[8];
    const float* Wl       = (const float*)d_in[9];   // 128 x 32
    const float* bl       = (const float*)d_in[10];
    float* out = (float*)d_out;

    char* ws = (char*)d_ws;
    int*   cnt      = (int*)ws;                 ws += align256((size_t)N_NODES * 4);
    int*   incl     = (int*)ws;                 ws += align256((size_t)N_NODES * 4);
    int*   bsum     = (int*)ws;                 ws += align256((size_t)SCAN_NB * 4);
    int*   boff     = (int*)ws;                 ws += align256((size_t)SCAN_NB * 4);
    int*   row_ptr  = (int*)ws;                 ws += align256((size_t)(N_NODES + 1) * 4);
    int*   fill_ptr = (int*)ws;                 ws += align256((size_t)N_NODES * 4);
    float* dinv     = (float*)ws;               ws += align256((size_t)N_NODES * 4);
    int*   gstart   = (int*)ws;                 ws += align256((size_t)(N_GRAPHS + 1) * 4);
    float* gsum     = (float*)ws;               ws += align256((size_t)N_GRAPHS * 64 * 4);
    float* gmax     = (float*)ws;               ws += align256((size_t)N_GRAPHS * 64 * 4);
    int*   csr_src  = (int*)ws;                 ws += align256((size_t)N_EDGES * 4);
    unsigned short* hwb = (unsigned short*)ws;  ws += align256((size_t)N_NODES * 64 * 2);
    float* h1       = (float*)ws;               ws += align256((size_t)N_NODES * 64 * 4);
    float* h2       = (float*)ws;               ws += align256((size_t)N_NODES * 64 * 4);

    hipLaunchKernelGGL(zero_i32, dim3((N_NODES + 255) / 256), dim3(256), 0, stream, cnt, N_NODES);
    // zero gsum+gmax (contiguous, 2*4096 floats)
    hipLaunchKernelGGL(zero_i32, dim3((2 * N_GRAPHS * 64 + 255) / 256), dim3(256), 0, stream,
                       (int*)gsum, 2 * N_GRAPHS * 64);
    hipLaunchKernelGGL(deg_kernel, dim3((N_EDGES + 255) / 256), dim3(256), 0, stream, ei, cnt);
    hipLaunchKernelGGL(scan_a, dim3(SCAN_NB), dim3(256), 0, stream, cnt, incl, bsum);
    hipLaunchKernelGGL(scan_b, dim3(1), dim3(256), 0, stream, bsum, boff);
    hipLaunchKernelGGL(scan_c, dim3(SCAN_NB), dim3(256), 0, stream,
                       cnt, incl, boff, row_ptr, fill_ptr, dinv);
    hipLaunchKernelGGL(fill_kernel,
                       dim3(FILL_RANGES * ((N_EDGES + 255) / 256)), dim3(256), 0, stream,
                       ei, fill_ptr, csr_src);
    hipLaunchKernelGGL(gstart_kernel, dim3(1), dim3(128), 0, stream, batch, gstart);

    const int mm_grid = (N_NODES + 63) / 64;
    const int agg_grid = (N_NODES + 3) / 4;  // 4 waves per block, wave per node

    // layer 1: x(128) @ W1 -> hw2 (dinv-scaled, bf16); agg -> h1
    hipLaunchKernelGGL((mfma_matmul<128>), dim3(mm_grid), dim3(256), 0, stream, x, W1, dinv, hwb);
    hipLaunchKernelGGL(agg_kernel, dim3(agg_grid), dim3(256), 0, stream,
                       hwb, row_ptr, csr_src, dinv, b1, h1);
    // layer 2
    hipLaunchKernelGGL((mfma_matmul<64>), dim3(mm_grid), dim3(256), 0, stream, h1, W2, dinv, hwb);
    hipLaunchKernelGGL(agg_kernel, dim3(agg_grid), dim3(256), 0, stream,
                       hwb, row_ptr, csr_src, dinv, b2, h2);
    // layer 3
    hipLaunchKernelGGL((mfma_matmul<64>), dim3(mm_grid), dim3(256), 0, stream, h2, W3, dinv, hwb);
    hipLaunchKernelGGL(agg_kernel, dim3(agg_grid), dim3(256), 0, stream,
                       hwb, row_ptr, csr_src, dinv, b3, h1);

    // two-phase pooling + final linear
    hipLaunchKernelGGL(pool_partial_kernel, dim3((N_NODES + 63) / 64), dim3(256), 0, stream,
                       h1, batch, gsum, gmax);
    hipLaunchKernelGGL(linear_kernel, dim3(N_GRAPHS), dim3(128), 0, stream,
                       gsum, gmax, gstart, Wl, bl, out);
}